// Round 12
// baseline (517.215 us; speedup 1.0000x reference)
//
#include <hip/hip_runtime.h>

typedef float f32x4 __attribute__((ext_vector_type(4)));
typedef float f32x16 __attribute__((ext_vector_type(16)));
typedef __bf16 bf16x8 __attribute__((ext_vector_type(8)));
typedef short s16x8 __attribute__((ext_vector_type(8)));
typedef unsigned short u16;
typedef unsigned int u32;

#define DEV static __device__ __forceinline__

constexpr int BATCH = 4;
constexpr int SQ    = 2048;
constexpr int SKV   = 2048;
constexpr int DMODEL= 512;
constexpr int NH    = 8;
constexpr int DH    = 64;
constexpr int MROWS = BATCH * SQ;      // 8192
constexpr float LN_EPS = 1e-5f;

DEV u16 f2bf(float f) {
    unsigned u = __builtin_bit_cast(unsigned, f);
    unsigned r = (u + 0x7FFFu + ((u >> 16) & 1u)) >> 16;
    return (u16)r;
}
DEV float bf2f(u16 h) { return __builtin_bit_cast(float, ((unsigned)h) << 16); }

DEV f32x4 mfma16(s16x8 a, s16x8 b, f32x4 c) {
    return __builtin_amdgcn_mfma_f32_16x16x32_bf16(
        __builtin_bit_cast(bf16x8, a), __builtin_bit_cast(bf16x8, b), c, 0, 0, 0);
}
DEV f32x16 mfma32(s16x8 a, s16x8 b, f32x16 c) {
    return __builtin_amdgcn_mfma_f32_32x32x16_bf16(
        __builtin_bit_cast(bf16x8, a), __builtin_bit_cast(bf16x8, b), c, 0, 0, 0);
}
DEV u32 cvtpk(float lo, float hi) {
    u32 r;
    asm("v_cvt_pk_bf16_f32 %0, %1, %2" : "=v"(r) : "v"(lo), "v"(hi));
    return r;
}

// ---------------------------------------------------------------------------
// DIAGNOSTIC: pure streaming-write probe over the attn region (537 MB).
// Block-contiguous, lane-coalesced, nontemporal. attn_kernel overwrites every
// byte afterwards, so output correctness is unaffected. Its rocprof row
// measures the chip's best-case streaming-write BW for this buffer.
// ---------------------------------------------------------------------------
__global__ __launch_bounds__(256) void probe_write(float* __restrict__ dst) {
    float* p = dst + (size_t)blockIdx.x * 65536;   // 256 KB per block
    f32x4 v = {1.f, 2.f, 3.f, 4.f};
    int t = threadIdx.x;
#pragma unroll
    for (int i = 0; i < 64; i++)
        __builtin_nontemporal_store(v, (f32x4*)(p + (size_t)i * 1024 + t * 4));
}

// ---------------------------------------------------------------------------
// LayerNorm + split to bf16 hi/lo. One wave per row of 512. Block = 4 rows.
// ---------------------------------------------------------------------------
__global__ __launch_bounds__(256) void ln_split_kernel(
    const float* __restrict__ X, const float* __restrict__ G, const float* __restrict__ Bt,
    u16* __restrict__ oh, u16* __restrict__ ol)
{
    int row  = blockIdx.x * 4 + (threadIdx.x >> 6);
    int lane = threadIdx.x & 63;
    const float4* xr = (const float4*)(X + (size_t)row * DMODEL);
    float4 a = xr[lane * 2], b = xr[lane * 2 + 1];
    float vv[8] = {a.x, a.y, a.z, a.w, b.x, b.y, b.z, b.w};
    float s = 0.f;
#pragma unroll
    for (int i = 0; i < 8; i++) s += vv[i];
#pragma unroll
    for (int o = 32; o; o >>= 1) s += __shfl_xor(s, o);
    float mu = s * (1.0f / DMODEL);
    float vs = 0.f;
#pragma unroll
    for (int i = 0; i < 8; i++) { float d = vv[i] - mu; vs += d * d; }
#pragma unroll
    for (int o = 32; o; o >>= 1) vs += __shfl_xor(vs, o);
    float rstd = rsqrtf(vs * (1.0f / DMODEL) + LN_EPS);

    const float4* g4 = (const float4*)G;
    const float4* b4 = (const float4*)Bt;
    float4 g0 = g4[lane * 2], g1 = g4[lane * 2 + 1];
    float4 c0 = b4[lane * 2], c1 = b4[lane * 2 + 1];
    float gg[8] = {g0.x, g0.y, g0.z, g0.w, g1.x, g1.y, g1.z, g1.w};
    float cc[8] = {c0.x, c0.y, c0.z, c0.w, c1.x, c1.y, c1.z, c1.w};

    s16x8 vh, vl;
#pragma unroll
    for (int i = 0; i < 8; i++) {
        float t = (vv[i] - mu) * rstd * gg[i] + cc[i];
        u16 h = f2bf(t);
        vh[i] = (short)h;
        vl[i] = (short)f2bf(t - bf2f(h));
    }
    size_t o0 = (size_t)row * DMODEL + lane * 8;
    *(s16x8*)(oh + o0) = vh;
    *(s16x8*)(ol + o0) = vl;
}

// ---------------------------------------------------------------------------
// Weight transpose + split, all 4 weights in one launch (blockIdx.y = which)
// ---------------------------------------------------------------------------
__global__ __launch_bounds__(256) void wsplit_kernel(
    const float* __restrict__ W0, const float* __restrict__ W1,
    const float* __restrict__ W2, const float* __restrict__ W3,
    u16* __restrict__ t0, u16* __restrict__ t1)
{
    int which = blockIdx.y;
    const float* W = which == 0 ? W0 : which == 1 ? W1 : which == 2 ? W2 : W3;
    u16* th = t0 + (size_t)which * 2 * 262144;
    u16* tl = th + 262144;
    (void)t1;
    int idx = blockIdx.x * 256 + threadIdx.x;     // idx = n*512 + k
    int n = idx >> 9, k = idx & 511;
    float v = W[(size_t)k * 512 + n];
    u16 h = f2bf(v);
    th[idx] = h;
    tl[idx] = f2bf(v - bf2f(h));
}

// ---------------------------------------------------------------------------
// Split-bf16 GEMM (unchanged; passes).
// ---------------------------------------------------------------------------
template<int MODE>
__global__ __launch_bounds__(256) void gemm_split(
    const u16* __restrict__ Ah, const u16* __restrict__ Al,
    const u16* __restrict__ Bh, const u16* __restrict__ Bl,
    void* __restrict__ out0, void* __restrict__ out1,
    const float* __restrict__ bias, float scl)
{
    constexpr int K  = 512;
    constexpr int LS = 72;
    __shared__ u16 lA[2][64][LS];
    __shared__ u16 lB[2][64][LS];

    int bm = blockIdx.x, bn = blockIdx.y;
    int tid = threadIdx.x, lane = tid & 63, wv = tid >> 6;
    int wm = (wv >> 1) * 32, wn = (wv & 1) * 32;
    int srow = tid >> 3, scol = (tid & 7) * 8;
    const size_t aoff0 = ((size_t)(bm * 64 + srow)) * K + scol;
    const size_t aoff1 = ((size_t)(bm * 64 + srow + 32)) * K + scol;
    const size_t boff0 = ((size_t)(bn * 64 + srow)) * K + scol;
    const size_t boff1 = ((size_t)(bn * 64 + srow + 32)) * K + scol;

    f32x4 acc[2][2] = {};

    for (int k0 = 0; k0 < K; k0 += 64) {
        *(int4*)&lA[0][srow][scol]      = *(const int4*)(Ah + aoff0 + k0);
        *(int4*)&lA[0][srow + 32][scol] = *(const int4*)(Ah + aoff1 + k0);
        *(int4*)&lA[1][srow][scol]      = *(const int4*)(Al + aoff0 + k0);
        *(int4*)&lA[1][srow + 32][scol] = *(const int4*)(Al + aoff1 + k0);
        *(int4*)&lB[0][srow][scol]      = *(const int4*)(Bh + boff0 + k0);
        *(int4*)&lB[0][srow + 32][scol] = *(const int4*)(Bh + boff1 + k0);
        *(int4*)&lB[1][srow][scol]      = *(const int4*)(Bl + boff0 + k0);
        *(int4*)&lB[1][srow + 32][scol] = *(const int4*)(Bl + boff1 + k0);
        __syncthreads();
        int fr = lane & 15, fg = (lane >> 4) * 8;
#pragma unroll
        for (int kk = 0; kk < 64; kk += 32) {
            s16x8 ah[2], al[2], bh[2], bl[2];
#pragma unroll
            for (int m_ = 0; m_ < 2; m_++) {
                ah[m_] = *(const s16x8*)&lA[0][wm + m_ * 16 + fr][kk + fg];
                al[m_] = *(const s16x8*)&lA[1][wm + m_ * 16 + fr][kk + fg];
            }
#pragma unroll
            for (int n_ = 0; n_ < 2; n_++) {
                bh[n_] = *(const s16x8*)&lB[0][wn + n_ * 16 + fr][kk + fg];
                bl[n_] = *(const s16x8*)&lB[1][wn + n_ * 16 + fr][kk + fg];
            }
#pragma unroll
            for (int m_ = 0; m_ < 2; m_++)
#pragma unroll
                for (int n_ = 0; n_ < 2; n_++) {
                    acc[m_][n_] = mfma16(ah[m_], bh[n_], acc[m_][n_]);
                    acc[m_][n_] = mfma16(ah[m_], bl[n_], acc[m_][n_]);
                    acc[m_][n_] = mfma16(al[m_], bh[n_], acc[m_][n_]);
                }
        }
        __syncthreads();
    }

    int fr = lane & 15, fq = lane >> 4;
#pragma unroll
    for (int m_ = 0; m_ < 2; m_++)
#pragma unroll
        for (int n_ = 0; n_ < 2; n_++)
#pragma unroll
            for (int r = 0; r < 4; r++) {
                int gm = bm * 64 + wm + m_ * 16 + fq * 4 + r;
                int gn = bn * 64 + wn + n_ * 16 + fr;
                float v = acc[m_][n_][r];
                if (MODE == 0) {
                    v *= scl;
                    int b_ = gm >> 11, s_ = gm & 2047, h_ = gn >> 6, d_ = gn & 63;
                    size_t adr = (((size_t)(b_ * NH + h_)) * SKV + s_) * DH + d_;
                    u16 hv = f2bf(v);
                    ((u16*)out0)[adr] = hv;
                    ((u16*)out1)[adr] = f2bf(v - bf2f(hv));
                } else if (MODE == 1) {
                    int b_ = gm >> 11, s_ = gm & 2047, h_ = gn >> 6, d_ = gn & 63;
                    size_t adr = (((size_t)(b_ * NH + h_)) * DH + d_) * SKV + s_;
                    ((u16*)out0)[adr] = f2bf(v);
                } else {
                    v += bias[gn];
                    ((float*)out0)[(size_t)gm * DMODEL + gn] = v;
                }
            }
}

// ---------------------------------------------------------------------------
// Streaming attention (R11 body, unchanged this round).
// 64 q-rows/block x kv-split x4: 8 waves. 4-tile batched 512B-segment stores.
// Layouts (mfma_f32_32x32x16_bf16, measured m74/m101):
//   A/B frag: row(col) = lane&31, k = 8*(lane>>5) + j, j=0..7
//   C:        col = lane&31,     row = (r&3) + 8*(r>>2) + 4*(lane>>5)
// ---------------------------------------------------------------------------
constexpr int BSTRIDE = 132;           // f32; 132*4B=528B, 16B-aligned rows

__global__ __launch_bounds__(512, 2) void attn_kernel(
    const u16* __restrict__ Qh, const u16* __restrict__ Ql,
    const u16* __restrict__ Kh, const u16* __restrict__ Kl,
    const u16* __restrict__ VT,
    float* __restrict__ attn, u16* __restrict__ ch, u16* __restrict__ cl)
{
    __shared__ float R[8][32 * BSTRIDE];   // per-wave transpose buf (16.9KB) / PV partials
    __shared__ float rs[8][32];            // rowsum partials
    int tid = threadIdx.x, lane = tid & 63, wid = tid >> 6;
    int h  = lane >> 5;
    int ql = lane & 31;
    int off = 8 * h;
    int t   = wid & 1;                 // q-subtile
    int kvq = wid >> 1;                // kv quarter

    // XCD-chunked bijective swizzle: 1024 blocks, 8 XCDs x 128; 4 bh per XCD
    int vb = (blockIdx.x & 7) * 128 + (blockIdx.x >> 3);
    int bh = vb >> 5;                  // (b*8+h_head)
    int qt2 = vb & 31;                 // 64-row q tile
    int q0 = qt2 * 64 + t * 32;
    const size_t base = (size_t)bh * (SKV * DH);
    int kt0 = kvq * 16;

    // ---- Q B-fragments (hi/lo): Q[q0+ql][16c + 8h + 0..7] ----
    s16x8 qfh[4], qfl[4];
    {
        const u16* qp  = Qh + base + ((size_t)(q0 + ql)) * DH + off;
        const u16* qlp = Ql + base + ((size_t)(q0 + ql)) * DH + off;
#pragma unroll
        for (int c = 0; c < 4; c++) {
            qfh[c] = *(const s16x8*)(qp + c * 16);
            qfl[c] = *(const s16x8*)(qlp + c * 16);
        }
    }

    // ---- pass 1: partial rowsum of exp(S), two accumulator chains ----
    float rsum = 0.f;
    for (int kt = kt0; kt < kt0 + 16; kt++) {
        size_t kb = base + ((size_t)(kt * 32 + ql)) * DH + off;
        f32x16 a1 = 0, a2 = 0;
#pragma unroll
        for (int c = 0; c < 4; c++) {
            s16x8 kh = *(const s16x8*)(Kh + kb + c * 16);
            s16x8 kl = *(const s16x8*)(Kl + kb + c * 16);
            a1 = mfma32(kh, qfh[c], a1);
            a2 = mfma32(kh, qfl[c], a2);
            a2 = mfma32(kl, qfh[c], a2);
        }
        f32x16 acc = a1 + a2;
#pragma unroll
        for (int r = 0; r < 16; r++) rsum += __expf(acc[r]);
    }
    rsum += __shfl_xor(rsum, 32);
    if (lane < 32) rs[wid][ql] = rsum;
    __syncthreads();
    float inv_l = 1.0f / (rs[t][ql] + rs[t + 2][ql] + rs[t + 4][ql] + rs[t + 6][ql]);

    // ---- pass 2: K prefetched one tile ahead; 4-tile batched stores ----
    f32x16 pv0 = 0, pv1 = 0;
    const u16* vbase = VT + (size_t)bh * (DH * SKV) + (size_t)ql * SKV + off;
    float* buf = R[wid];

    s16x8 kA[4], klA[4];               // current tile's K frags (loaded last iter)
    {
        size_t kb = base + ((size_t)(kt0 * 32 + ql)) * DH + off;
#pragma unroll
        for (int c = 0; c < 4; c++) {
            kA[c]  = *(const s16x8*)(Kh + kb + c * 16);
            klA[c] = *(const s16x8*)(Kl + kb + c * 16);
        }
    }

    for (int g = 0; g < 4; g++) {
#pragma unroll
        for (int ii = 0; ii < 4; ii++) {
            int i = g * 4 + ii;
            int kt = kt0 + i;
            // --- this tile's V loads (issued before any stores of this group) ---
            const u16* vp = vbase + kt * 32;
            s16x8 v00 = *(const s16x8*)(vp);
            s16x8 v01 = *(const s16x8*)(vp + 16);
            s16x8 v10 = *(const s16x8*)(vp + (size_t)32 * SKV);
            s16x8 v11 = *(const s16x8*)(vp + (size_t)32 * SKV + 16);
            // --- next tile's K prefetch ---
            s16x8 kB[4], klB[4];
            if (i + 1 < 16) {
                size_t kb = base + ((size_t)((kt + 1) * 32 + ql)) * DH + off;
#pragma unroll
                for (int c = 0; c < 4; c++) {
                    kB[c]  = *(const s16x8*)(Kh + kb + c * 16);
                    klB[c] = *(const s16x8*)(Kl + kb + c * 16);
                }
            }
            // --- QK^T from prefetched regs ---
            f32x16 a1 = 0, a2 = 0;
#pragma unroll
            for (int c = 0; c < 4; c++) {
                a1 = mfma32(kA[c], qfh[c], a1);
                a2 = mfma32(kA[c], qfl[c], a2);
                a2 = mfma32(klA[c], qfh[c], a2);
            }
            f32x16 acc = a1 + a2;
#pragma unroll
            for (int r = 0; r < 16; r++) acc[r] = __expf(acc[r]) * inv_l;

            // --- PV: pack to bf16 + permlane -> B-frags ---
            u32 O0[4], O1[4];
#pragma unroll
            for (int gg_ = 0; gg_ < 4; gg_++) {
                O0[gg_] = cvtpk(acc[4 * gg_ + 0], acc[4 * gg_ + 1]);
                O1[gg_] = cvtpk(acc[4 * gg_ + 2], acc[4 * gg_ + 3]);
            }
            {
                u32 a = O0[0], b = O0[1], c = O1[0], d = O1[1];
                asm("v_permlane32_swap_b32 %0, %1" : "+v"(a), "+v"(b));
                asm("v_permlane32_swap_b32 %0, %1" : "+v"(c), "+v"(d));
                uint4 w = {a, c, b, d};
                s16x8 bf = __builtin_bit_cast(s16x8, w);
                pv0 = mfma32(v00, bf, pv0);
                pv1 = mfma32(v10, bf, pv1);
            }
            {
                u32 a = O0[2], b = O0[3], c = O1[2], d = O1[3];
                asm("v_permlane32_swap_b32 %0, %1" : "+v"(a), "+v"(b));
                asm("v_permlane32_swap_b32 %0, %1" : "+v"(c), "+v"(d));
                uint4 w = {a, c, b, d};
                s16x8 bf = __builtin_bit_cast(s16x8, w);
                pv0 = mfma32(v01, bf, pv0);
                pv1 = mfma32(v11, bf, pv1);
            }

            // --- LDS transpose into group buffer: row=q(=ql), col=ii*32+crow ---
#pragma unroll
            for (int r = 0; r < 16; r++)
                buf[ql * BSTRIDE + ii * 32 + (r & 3) + 8 * (r >> 2) + 4 * h] = acc[r];

#pragma unroll
            for (int c = 0; c < 4; c++) { kA[c] = kB[c]; klA[c] = klB[c]; }
        }

        // --- store burst: 16 insts, each 2 rows x 512B contiguous ---
        {
            int cl4 = (lane & 31) * 4;
            int rh  = lane >> 5;
            size_t gbase = (size_t)(bh * SQ + q0) * SKV + kt0 * 32 + g * 128 + cl4;
#pragma unroll
            for (int j = 0; j < 16; j++) {
                int row = 2 * j + rh;
                f32x4 o = *(const f32x4*)&buf[row * BSTRIDE + cl4];
                __builtin_nontemporal_store(o, (f32x4*)&attn[gbase + (size_t)row * SKV]);
            }
        }
    }

    // ---- write PV partials to own LDS region (buf dead) ----
#pragma unroll
    for (int r = 0; r < 16; r++) {
        R[wid][r * 64 + lane]        = pv0[r];
        R[wid][1024 + r * 64 + lane] = pv1[r];
    }
    __syncthreads();

    // ---- waves 0..3 reduce 4 kv partials for (qtile=w&1, d-half=w>>1) ----
    if (wid < 4) {
        int tt = wid & 1, X = wid >> 1;
        float s[16];
#pragma unroll
        for (int r = 0; r < 16; r++)
            s[r] = R[0 + tt][X * 1024 + r * 64 + lane] + R[2 + tt][X * 1024 + r * 64 + lane]
                 + R[4 + tt][X * 1024 + r * 64 + lane] + R[6 + tt][X * 1024 + r * 64 + lane];
        int b_ = bh >> 3, hh = bh & 7;
        size_t rowa = ((size_t)(b_ * SQ + qt2 * 64 + tt * 32 + ql)) * DMODEL
                    + hh * 64 + X * 32 + 4 * h;
#pragma unroll
        for (int g = 0; g < 4; g++) {
            u16 hv[4], lv[4];
#pragma unroll
            for (int i = 0; i < 4; i++) {
                float v = s[4 * g + i];
                hv[i] = f2bf(v);
                lv[i] = f2bf(v - bf2f(hv[i]));
            }
            *(ushort4*)(ch + rowa + 8 * g) = *(ushort4*)hv;
            *(ushort4*)(cl + rowa + 8 * g) = *(ushort4*)lv;
        }
    }
}

// ---------------------------------------------------------------------------
extern "C" void kernel_launch(void* const* d_in, const int* in_sizes, int n_in,
                              void* d_out, int out_size, void* d_ws, size_t ws_size,
                              hipStream_t stream)
{
    const float* x   = (const float*)d_in[0];
    const float* y   = (const float*)d_in[1];
    const float* lqg = (const float*)d_in[2];
    const float* lqb = (const float*)d_in[3];
    const float* lkg = (const float*)d_in[4];
    const float* lkb = (const float*)d_in[5];
    const float* Wq  = (const float*)d_in[6];
    const float* Wk  = (const float*)d_in[7];
    const float* Wv  = (const float*)d_in[8];
    const float* Wo  = (const float*)d_in[9];
    const float* bo  = (const float*)d_in[10];

    char* ws = (char*)d_ws;
    size_t off = 0;
    auto alloc = [&](size_t nelem) -> u16* {
        u16* p = (u16*)(ws + off);
        off += (nelem * 2 + 255) & ~(size_t)255;
        return p;
    };
    const size_t NROW = (size_t)MROWS * DMODEL;
    u16* xnh = alloc(NROW);  u16* xnl = alloc(NROW);
    u16* ynh = alloc(NROW);  u16* ynl = alloc(NROW);
    u16* wbase = alloc(4 * 2 * 262144);
    u16* wqh = wbase + 0 * 2 * 262144; u16* wql = wqh + 262144;
    u16* wkh = wbase + 1 * 2 * 262144; u16* wkl = wkh + 262144;
    u16* wvh = wbase + 2 * 2 * 262144; u16* wvl = wvh + 262144;
    u16* woh = wbase + 3 * 2 * 262144; u16* wol = woh + 262144;
    u16* qh_ = alloc(NROW);  u16* ql_ = alloc(NROW);
    u16* kh_ = alloc(NROW);  u16* kl_ = alloc(NROW);
    u16* vt_ = alloc(NROW);
    u16* cth = alloc(NROW);  u16* ctl = alloc(NROW);

    float* outp  = (float*)d_out;
    float* attnp = outp + (size_t)MROWS * DMODEL;

    ln_split_kernel<<<MROWS / 4, 256, 0, stream>>>(x, lqg, lqb, xnh, xnl);
    ln_split_kernel<<<MROWS / 4, 256, 0, stream>>>(y, lkg, lkb, ynh, ynl);
    wsplit_kernel<<<dim3(1024, 4), 256, 0, stream>>>(Wq, Wk, Wv, Wo, wbase, nullptr);

    dim3 gg(MROWS / 64, 512 / 64);
    gemm_split<0><<<gg, 256, 0, stream>>>(xnh, xnl, wqh, wql, qh_, ql_, nullptr, 0.125f);
    gemm_split<0><<<gg, 256, 0, stream>>>(ynh, ynl, wkh, wkl, kh_, kl_, nullptr, 1.0f);
    gemm_split<1><<<gg, 256, 0, stream>>>(ynh, ynl, wvh, wvl, vt_, nullptr, nullptr, 1.0f);

    // DIAGNOSTIC: pure-write roofline probe over the attn region (537 MB);
    // attn_kernel overwrites every byte, so correctness is unaffected.
    probe_write<<<2048, 256, 0, stream>>>(attnp);

    attn_kernel<<<1024, 512, 0, stream>>>(qh_, ql_, kh_, kl_, vt_, attnp, cth, ctl);

    gemm_split<2><<<gg, 256, 0, stream>>>(cth, ctl, woh, wol, (void*)outp, nullptr, bo, 1.0f);
}

// Round 13
// 422.015 us; speedup vs baseline: 1.2256x; 1.2256x over previous
//
#include <hip/hip_runtime.h>

typedef float f32x4 __attribute__((ext_vector_type(4)));
typedef float f32x16 __attribute__((ext_vector_type(16)));
typedef __bf16 bf16x8 __attribute__((ext_vector_type(8)));
typedef short s16x8 __attribute__((ext_vector_type(8)));
typedef unsigned short u16;
typedef unsigned int u32;

#define DEV static __device__ __forceinline__

constexpr int BATCH = 4;
constexpr int SQ    = 2048;
constexpr int SKV   = 2048;
constexpr int DMODEL= 512;
constexpr int NH    = 8;
constexpr int DH    = 64;
constexpr int MROWS = BATCH * SQ;      // 8192
constexpr float LN_EPS = 1e-5f;

DEV u16 f2bf(float f) {
    unsigned u = __builtin_bit_cast(unsigned, f);
    unsigned r = (u + 0x7FFFu + ((u >> 16) & 1u)) >> 16;
    return (u16)r;
}
DEV float bf2f(u16 h) { return __builtin_bit_cast(float, ((unsigned)h) << 16); }

DEV f32x4 mfma16(s16x8 a, s16x8 b, f32x4 c) {
    return __builtin_amdgcn_mfma_f32_16x16x32_bf16(
        __builtin_bit_cast(bf16x8, a), __builtin_bit_cast(bf16x8, b), c, 0, 0, 0);
}
DEV f32x16 mfma32(s16x8 a, s16x8 b, f32x16 c) {
    return __builtin_amdgcn_mfma_f32_32x32x16_bf16(
        __builtin_bit_cast(bf16x8, a), __builtin_bit_cast(bf16x8, b), c, 0, 0, 0);
}
DEV u32 cvtpk(float lo, float hi) {
    u32 r;
    asm("v_cvt_pk_bf16_f32 %0, %1, %2" : "=v"(r) : "v"(lo), "v"(hi));
    return r;
}

// ---------------------------------------------------------------------------
// LayerNorm + split to bf16 hi/lo. One wave per row of 512. Block = 4 rows.
// ---------------------------------------------------------------------------
__global__ __launch_bounds__(256) void ln_split_kernel(
    const float* __restrict__ X, const float* __restrict__ G, const float* __restrict__ Bt,
    u16* __restrict__ oh, u16* __restrict__ ol)
{
    int row  = blockIdx.x * 4 + (threadIdx.x >> 6);
    int lane = threadIdx.x & 63;
    const float4* xr = (const float4*)(X + (size_t)row * DMODEL);
    float4 a = xr[lane * 2], b = xr[lane * 2 + 1];
    float vv[8] = {a.x, a.y, a.z, a.w, b.x, b.y, b.z, b.w};
    float s = 0.f;
#pragma unroll
    for (int i = 0; i < 8; i++) s += vv[i];
#pragma unroll
    for (int o = 32; o; o >>= 1) s += __shfl_xor(s, o);
    float mu = s * (1.0f / DMODEL);
    float vs = 0.f;
#pragma unroll
    for (int i = 0; i < 8; i++) { float d = vv[i] - mu; vs += d * d; }
#pragma unroll
    for (int o = 32; o; o >>= 1) vs += __shfl_xor(vs, o);
    float rstd = rsqrtf(vs * (1.0f / DMODEL) + LN_EPS);

    const float4* g4 = (const float4*)G;
    const float4* b4 = (const float4*)Bt;
    float4 g0 = g4[lane * 2], g1 = g4[lane * 2 + 1];
    float4 c0 = b4[lane * 2], c1 = b4[lane * 2 + 1];
    float gg[8] = {g0.x, g0.y, g0.z, g0.w, g1.x, g1.y, g1.z, g1.w};
    float cc[8] = {c0.x, c0.y, c0.z, c0.w, c1.x, c1.y, c1.z, c1.w};

    s16x8 vh, vl;
#pragma unroll
    for (int i = 0; i < 8; i++) {
        float t = (vv[i] - mu) * rstd * gg[i] + cc[i];
        u16 h = f2bf(t);
        vh[i] = (short)h;
        vl[i] = (short)f2bf(t - bf2f(h));
    }
    size_t o0 = (size_t)row * DMODEL + lane * 8;
    *(s16x8*)(oh + o0) = vh;
    *(s16x8*)(ol + o0) = vl;
}

// ---------------------------------------------------------------------------
// Weight transpose + split, all 4 weights in one launch (blockIdx.y = which)
// ---------------------------------------------------------------------------
__global__ __launch_bounds__(256) void wsplit_kernel(
    const float* __restrict__ W0, const float* __restrict__ W1,
    const float* __restrict__ W2, const float* __restrict__ W3,
    u16* __restrict__ t0, u16* __restrict__ t1)
{
    int which = blockIdx.y;
    const float* W = which == 0 ? W0 : which == 1 ? W1 : which == 2 ? W2 : W3;
    u16* th = t0 + (size_t)which * 2 * 262144;
    u16* tl = th + 262144;
    (void)t1;
    int idx = blockIdx.x * 256 + threadIdx.x;     // idx = n*512 + k
    int n = idx >> 9, k = idx & 511;
    float v = W[(size_t)k * 512 + n];
    u16 h = f2bf(v);
    th[idx] = h;
    tl[idx] = f2bf(v - bf2f(h));
}

// ---------------------------------------------------------------------------
// Split-bf16 GEMM (unchanged; passes).
// ---------------------------------------------------------------------------
template<int MODE>
__global__ __launch_bounds__(256) void gemm_split(
    const u16* __restrict__ Ah, const u16* __restrict__ Al,
    const u16* __restrict__ Bh, const u16* __restrict__ Bl,
    void* __restrict__ out0, void* __restrict__ out1,
    const float* __restrict__ bias, float scl)
{
    constexpr int K  = 512;
    constexpr int LS = 72;
    __shared__ u16 lA[2][64][LS];
    __shared__ u16 lB[2][64][LS];

    int bm = blockIdx.x, bn = blockIdx.y;
    int tid = threadIdx.x, lane = tid & 63, wv = tid >> 6;
    int wm = (wv >> 1) * 32, wn = (wv & 1) * 32;
    int srow = tid >> 3, scol = (tid & 7) * 8;
    const size_t aoff0 = ((size_t)(bm * 64 + srow)) * K + scol;
    const size_t aoff1 = ((size_t)(bm * 64 + srow + 32)) * K + scol;
    const size_t boff0 = ((size_t)(bn * 64 + srow)) * K + scol;
    const size_t boff1 = ((size_t)(bn * 64 + srow + 32)) * K + scol;

    f32x4 acc[2][2] = {};

    for (int k0 = 0; k0 < K; k0 += 64) {
        *(int4*)&lA[0][srow][scol]      = *(const int4*)(Ah + aoff0 + k0);
        *(int4*)&lA[0][srow + 32][scol] = *(const int4*)(Ah + aoff1 + k0);
        *(int4*)&lA[1][srow][scol]      = *(const int4*)(Al + aoff0 + k0);
        *(int4*)&lA[1][srow + 32][scol] = *(const int4*)(Al + aoff1 + k0);
        *(int4*)&lB[0][srow][scol]      = *(const int4*)(Bh + boff0 + k0);
        *(int4*)&lB[0][srow + 32][scol] = *(const int4*)(Bh + boff1 + k0);
        *(int4*)&lB[1][srow][scol]      = *(const int4*)(Bl + boff0 + k0);
        *(int4*)&lB[1][srow + 32][scol] = *(const int4*)(Bl + boff1 + k0);
        __syncthreads();
        int fr = lane & 15, fg = (lane >> 4) * 8;
#pragma unroll
        for (int kk = 0; kk < 64; kk += 32) {
            s16x8 ah[2], al[2], bh[2], bl[2];
#pragma unroll
            for (int m_ = 0; m_ < 2; m_++) {
                ah[m_] = *(const s16x8*)&lA[0][wm + m_ * 16 + fr][kk + fg];
                al[m_] = *(const s16x8*)&lA[1][wm + m_ * 16 + fr][kk + fg];
            }
#pragma unroll
            for (int n_ = 0; n_ < 2; n_++) {
                bh[n_] = *(const s16x8*)&lB[0][wn + n_ * 16 + fr][kk + fg];
                bl[n_] = *(const s16x8*)&lB[1][wn + n_ * 16 + fr][kk + fg];
            }
#pragma unroll
            for (int m_ = 0; m_ < 2; m_++)
#pragma unroll
                for (int n_ = 0; n_ < 2; n_++) {
                    acc[m_][n_] = mfma16(ah[m_], bh[n_], acc[m_][n_]);
                    acc[m_][n_] = mfma16(ah[m_], bl[n_], acc[m_][n_]);
                    acc[m_][n_] = mfma16(al[m_], bh[n_], acc[m_][n_]);
                }
        }
        __syncthreads();
    }

    int fr = lane & 15, fq = lane >> 4;
#pragma unroll
    for (int m_ = 0; m_ < 2; m_++)
#pragma unroll
        for (int n_ = 0; n_ < 2; n_++)
#pragma unroll
            for (int r = 0; r < 4; r++) {
                int gm = bm * 64 + wm + m_ * 16 + fq * 4 + r;
                int gn = bn * 64 + wn + n_ * 16 + fr;
                float v = acc[m_][n_][r];
                if (MODE == 0) {
                    v *= scl;
                    int b_ = gm >> 11, s_ = gm & 2047, h_ = gn >> 6, d_ = gn & 63;
                    size_t adr = (((size_t)(b_ * NH + h_)) * SKV + s_) * DH + d_;
                    u16 hv = f2bf(v);
                    ((u16*)out0)[adr] = hv;
                    ((u16*)out1)[adr] = f2bf(v - bf2f(hv));
                } else if (MODE == 1) {
                    int b_ = gm >> 11, s_ = gm & 2047, h_ = gn >> 6, d_ = gn & 63;
                    size_t adr = (((size_t)(b_ * NH + h_)) * DH + d_) * SKV + s_;
                    ((u16*)out0)[adr] = f2bf(v);
                } else {
                    v += bias[gn];
                    ((float*)out0)[(size_t)gm * DMODEL + gn] = v;
                }
            }
}

// ---------------------------------------------------------------------------
// Streaming attention, 64 q-rows/block x kv-split x4: 8 waves (512 thr).
// R13: BOTH V and K prefetched one tile ahead. vmcnt retires IN ORDER
// (probe R12: pure stores hit 5.6 TB/s; our 1.6 TB/s was loads-after-stores
// coupling). With V+K prefetch, every load consumed in body i was issued
// BEFORE the previous store burst, so MFMA waits never imply store drain.
//
// Layouts (mfma_f32_32x32x16_bf16, measured m74/m101):
//   A/B frag: row(col) = lane&31, k = 8*(lane>>5) + j, j=0..7
//   C:        col = lane&31,     row = (r&3) + 8*(r>>2) + 4*(lane>>5)
// ---------------------------------------------------------------------------
constexpr int BSTRIDE = 132;           // f32; 132*4B=528B, 16B-aligned rows

__global__ __launch_bounds__(512) void attn_kernel(
    const u16* __restrict__ Qh, const u16* __restrict__ Ql,
    const u16* __restrict__ Kh, const u16* __restrict__ Kl,
    const u16* __restrict__ VT,
    float* __restrict__ attn, u16* __restrict__ ch, u16* __restrict__ cl)
{
    __shared__ float R[8][32 * BSTRIDE];   // per-wave transpose buf (16.9KB) / PV partials
    __shared__ float rs[8][32];            // rowsum partials
    int tid = threadIdx.x, lane = tid & 63, wid = tid >> 6;
    int h  = lane >> 5;
    int ql = lane & 31;
    int off = 8 * h;
    int t   = wid & 1;                 // q-subtile
    int kvq = wid >> 1;                // kv quarter

    // XCD-chunked bijective swizzle: 1024 blocks, 8 XCDs x 128; 4 bh per XCD
    int vb = (blockIdx.x & 7) * 128 + (blockIdx.x >> 3);
    int bh = vb >> 5;                  // (b*8+h_head)
    int qt2 = vb & 31;                 // 64-row q tile
    int q0 = qt2 * 64 + t * 32;
    const size_t base = (size_t)bh * (SKV * DH);
    int kt0 = kvq * 16;

    // ---- Q B-fragments (hi/lo): Q[q0+ql][16c + 8h + 0..7] ----
    s16x8 qfh[4], qfl[4];
    {
        const u16* qp  = Qh + base + ((size_t)(q0 + ql)) * DH + off;
        const u16* qlp = Ql + base + ((size_t)(q0 + ql)) * DH + off;
#pragma unroll
        for (int c = 0; c < 4; c++) {
            qfh[c] = *(const s16x8*)(qp + c * 16);
            qfl[c] = *(const s16x8*)(qlp + c * 16);
        }
    }

    // ---- pass 1: partial rowsum of exp(S), two accumulator chains ----
    float rsum = 0.f;
    for (int kt = kt0; kt < kt0 + 16; kt++) {
        size_t kb = base + ((size_t)(kt * 32 + ql)) * DH + off;
        f32x16 a1 = 0, a2 = 0;
#pragma unroll
        for (int c = 0; c < 4; c++) {
            s16x8 kh = *(const s16x8*)(Kh + kb + c * 16);
            s16x8 kl = *(const s16x8*)(Kl + kb + c * 16);
            a1 = mfma32(kh, qfh[c], a1);
            a2 = mfma32(kh, qfl[c], a2);
            a2 = mfma32(kl, qfh[c], a2);
        }
        f32x16 acc = a1 + a2;
#pragma unroll
        for (int r = 0; r < 16; r++) rsum += __expf(acc[r]);
    }
    rsum += __shfl_xor(rsum, 32);
    if (lane < 32) rs[wid][ql] = rsum;
    __syncthreads();
    float inv_l = 1.0f / (rs[t][ql] + rs[t + 2][ql] + rs[t + 4][ql] + rs[t + 6][ql]);

    // ---- pass 2: V AND K prefetched one tile ahead; 4-tile batched stores ----
    f32x16 pv0 = 0, pv1 = 0;
    const u16* vbase = VT + (size_t)bh * (DH * SKV) + (size_t)ql * SKV + off;
    float* buf = R[wid];

    s16x8 kA[4], klA[4], vA[4];        // current tile's K and V frags
    {
        size_t kb = base + ((size_t)(kt0 * 32 + ql)) * DH + off;
        const u16* vp = vbase + kt0 * 32;
#pragma unroll
        for (int c = 0; c < 4; c++) {
            kA[c]  = *(const s16x8*)(Kh + kb + c * 16);
            klA[c] = *(const s16x8*)(Kl + kb + c * 16);
        }
        vA[0] = *(const s16x8*)(vp);
        vA[1] = *(const s16x8*)(vp + 16);
        vA[2] = *(const s16x8*)(vp + (size_t)32 * SKV);
        vA[3] = *(const s16x8*)(vp + (size_t)32 * SKV + 16);
    }

    for (int g = 0; g < 4; g++) {
#pragma unroll
        for (int ii = 0; ii < 4; ii++) {
            int i = g * 4 + ii;
            int kt = kt0 + i;
            // --- prefetch NEXT tile's K and V (before any store of this group) ---
            s16x8 kB[4], klB[4], vB[4];
            if (i + 1 < 16) {
                size_t kb = base + ((size_t)((kt + 1) * 32 + ql)) * DH + off;
                const u16* vp = vbase + (kt + 1) * 32;
#pragma unroll
                for (int c = 0; c < 4; c++) {
                    kB[c]  = *(const s16x8*)(Kh + kb + c * 16);
                    klB[c] = *(const s16x8*)(Kl + kb + c * 16);
                }
                vB[0] = *(const s16x8*)(vp);
                vB[1] = *(const s16x8*)(vp + 16);
                vB[2] = *(const s16x8*)(vp + (size_t)32 * SKV);
                vB[3] = *(const s16x8*)(vp + (size_t)32 * SKV + 16);
            }
            // --- QK^T from prefetched regs ---
            f32x16 a1 = 0, a2 = 0;
#pragma unroll
            for (int c = 0; c < 4; c++) {
                a1 = mfma32(kA[c], qfh[c], a1);
                a2 = mfma32(kA[c], qfl[c], a2);
                a2 = mfma32(klA[c], qfh[c], a2);
            }
            f32x16 acc = a1 + a2;
#pragma unroll
            for (int r = 0; r < 16; r++) acc[r] = __expf(acc[r]) * inv_l;

            // --- PV: pack to bf16 + permlane -> B-frags (V from prefetched regs) ---
            u32 O0[4], O1[4];
#pragma unroll
            for (int gg_ = 0; gg_ < 4; gg_++) {
                O0[gg_] = cvtpk(acc[4 * gg_ + 0], acc[4 * gg_ + 1]);
                O1[gg_] = cvtpk(acc[4 * gg_ + 2], acc[4 * gg_ + 3]);
            }
            {
                u32 a = O0[0], b = O0[1], c = O1[0], d = O1[1];
                asm("v_permlane32_swap_b32 %0, %1" : "+v"(a), "+v"(b));
                asm("v_permlane32_swap_b32 %0, %1" : "+v"(c), "+v"(d));
                uint4 w = {a, c, b, d};
                s16x8 bf = __builtin_bit_cast(s16x8, w);
                pv0 = mfma32(vA[0], bf, pv0);
                pv1 = mfma32(vA[2], bf, pv1);
            }
            {
                u32 a = O0[2], b = O0[3], c = O1[2], d = O1[3];
                asm("v_permlane32_swap_b32 %0, %1" : "+v"(a), "+v"(b));
                asm("v_permlane32_swap_b32 %0, %1" : "+v"(c), "+v"(d));
                uint4 w = {a, c, b, d};
                s16x8 bf = __builtin_bit_cast(s16x8, w);
                pv0 = mfma32(vA[1], bf, pv0);
                pv1 = mfma32(vA[3], bf, pv1);
            }

            // --- LDS transpose into group buffer: row=q(=ql), col=ii*32+crow ---
#pragma unroll
            for (int r = 0; r < 16; r++)
                buf[ql * BSTRIDE + ii * 32 + (r & 3) + 8 * (r >> 2) + 4 * h] = acc[r];

#pragma unroll
            for (int c = 0; c < 4; c++) { kA[c] = kB[c]; klA[c] = klB[c]; }
#pragma unroll
            for (int c = 0; c < 4; c++) vA[c] = vB[c];
        }

        // --- store burst: 16 insts, each 2 rows x 512B contiguous ---
        {
            int cl4 = (lane & 31) * 4;
            int rh  = lane >> 5;
            size_t gbase = (size_t)(bh * SQ + q0) * SKV + kt0 * 32 + g * 128 + cl4;
#pragma unroll
            for (int j = 0; j < 16; j++) {
                int row = 2 * j + rh;
                f32x4 o = *(const f32x4*)&buf[row * BSTRIDE + cl4];
                __builtin_nontemporal_store(o, (f32x4*)&attn[gbase + (size_t)row * SKV]);
            }
        }
    }

    // ---- write PV partials to own LDS region (buf dead) ----
#pragma unroll
    for (int r = 0; r < 16; r++) {
        R[wid][r * 64 + lane]        = pv0[r];
        R[wid][1024 + r * 64 + lane] = pv1[r];
    }
    __syncthreads();

    // ---- waves 0..3 reduce 4 kv partials for (qtile=w&1, d-half=w>>1) ----
    if (wid < 4) {
        int tt = wid & 1, X = wid >> 1;
        float s[16];
#pragma unroll
        for (int r = 0; r < 16; r++)
            s[r] = R[0 + tt][X * 1024 + r * 64 + lane] + R[2 + tt][X * 1024 + r * 64 + lane]
                 + R[4 + tt][X * 1024 + r * 64 + lane] + R[6 + tt][X * 1024 + r * 64 + lane];
        int b_ = bh >> 3, hh = bh & 7;
        size_t rowa = ((size_t)(b_ * SQ + qt2 * 64 + tt * 32 + ql)) * DMODEL
                    + hh * 64 + X * 32 + 4 * h;
#pragma unroll
        for (int g = 0; g < 4; g++) {
            u16 hv[4], lv[4];
#pragma unroll
            for (int i = 0; i < 4; i++) {
                float v = s[4 * g + i];
                hv[i] = f2bf(v);
                lv[i] = f2bf(v - bf2f(hv[i]));
            }
            *(ushort4*)(ch + rowa + 8 * g) = *(ushort4*)hv;
            *(ushort4*)(cl + rowa + 8 * g) = *(ushort4*)lv;
        }
    }
}

// ---------------------------------------------------------------------------
extern "C" void kernel_launch(void* const* d_in, const int* in_sizes, int n_in,
                              void* d_out, int out_size, void* d_ws, size_t ws_size,
                              hipStream_t stream)
{
    const float* x   = (const float*)d_in[0];
    const float* y   = (const float*)d_in[1];
    const float* lqg = (const float*)d_in[2];
    const float* lqb = (const float*)d_in[3];
    const float* lkg = (const float*)d_in[4];
    const float* lkb = (const float*)d_in[5];
    const float* Wq  = (const float*)d_in[6];
    const float* Wk  = (const float*)d_in[7];
    const float* Wv  = (const float*)d_in[8];
    const float* Wo  = (const float*)d_in[9];
    const float* bo  = (const float*)d_in[10];

    char* ws = (char*)d_ws;
    size_t off = 0;
    auto alloc = [&](size_t nelem) -> u16* {
        u16* p = (u16*)(ws + off);
        off += (nelem * 2 + 255) & ~(size_t)255;
        return p;
    };
    const size_t NROW = (size_t)MROWS * DMODEL;
    u16* xnh = alloc(NROW);  u16* xnl = alloc(NROW);
    u16* ynh = alloc(NROW);  u16* ynl = alloc(NROW);
    u16* wbase = alloc(4 * 2 * 262144);
    u16* wqh = wbase + 0 * 2 * 262144; u16* wql = wqh + 262144;
    u16* wkh = wbase + 1 * 2 * 262144; u16* wkl = wkh + 262144;
    u16* wvh = wbase + 2 * 2 * 262144; u16* wvl = wvh + 262144;
    u16* woh = wbase + 3 * 2 * 262144; u16* wol = woh + 262144;
    u16* qh_ = alloc(NROW);  u16* ql_ = alloc(NROW);
    u16* kh_ = alloc(NROW);  u16* kl_ = alloc(NROW);
    u16* vt_ = alloc(NROW);
    u16* cth = alloc(NROW);  u16* ctl = alloc(NROW);

    float* outp  = (float*)d_out;
    float* attnp = outp + (size_t)MROWS * DMODEL;

    ln_split_kernel<<<MROWS / 4, 256, 0, stream>>>(x, lqg, lqb, xnh, xnl);
    ln_split_kernel<<<MROWS / 4, 256, 0, stream>>>(y, lkg, lkb, ynh, ynl);
    wsplit_kernel<<<dim3(1024, 4), 256, 0, stream>>>(Wq, Wk, Wv, Wo, wbase, nullptr);

    dim3 gg(MROWS / 64, 512 / 64);
    gemm_split<0><<<gg, 256, 0, stream>>>(xnh, xnl, wqh, wql, qh_, ql_, nullptr, 0.125f);
    gemm_split<0><<<gg, 256, 0, stream>>>(ynh, ynl, wkh, wkl, kh_, kl_, nullptr, 1.0f);
    gemm_split<1><<<gg, 256, 0, stream>>>(ynh, ynl, wvh, wvl, vt_, nullptr, nullptr, 1.0f);

    attn_kernel<<<1024, 512, 0, stream>>>(qh_, ql_, kh_, kl_, vt_, attnp, cth, ctl);

    gemm_split<2><<<gg, 256, 0, stream>>>(cth, ctl, woh, wol, (void*)outp, nullptr, bo, 1.0f);
}

// Round 14
// 411.304 us; speedup vs baseline: 1.2575x; 1.0260x over previous
//
#include <hip/hip_runtime.h>

typedef float f32x4 __attribute__((ext_vector_type(4)));
typedef float f32x16 __attribute__((ext_vector_type(16)));
typedef __bf16 bf16x8 __attribute__((ext_vector_type(8)));
typedef short s16x8 __attribute__((ext_vector_type(8)));
typedef unsigned short u16;
typedef unsigned int u32;

#define DEV static __device__ __forceinline__

constexpr int BATCH = 4;
constexpr int SQ    = 2048;
constexpr int SKV   = 2048;
constexpr int DMODEL= 512;
constexpr int NH    = 8;
constexpr int DH    = 64;
constexpr int MROWS = BATCH * SQ;      // 8192
constexpr float LN_EPS = 1e-5f;

DEV u16 f2bf(float f) {
    unsigned u = __builtin_bit_cast(unsigned, f);
    unsigned r = (u + 0x7FFFu + ((u >> 16) & 1u)) >> 16;
    return (u16)r;
}
DEV float bf2f(u16 h) { return __builtin_bit_cast(float, ((unsigned)h) << 16); }

DEV f32x4 mfma16(s16x8 a, s16x8 b, f32x4 c) {
    return __builtin_amdgcn_mfma_f32_16x16x32_bf16(
        __builtin_bit_cast(bf16x8, a), __builtin_bit_cast(bf16x8, b), c, 0, 0, 0);
}
DEV f32x16 mfma32(s16x8 a, s16x8 b, f32x16 c) {
    return __builtin_amdgcn_mfma_f32_32x32x16_bf16(
        __builtin_bit_cast(bf16x8, a), __builtin_bit_cast(bf16x8, b), c, 0, 0, 0);
}
DEV u32 cvtpk(float lo, float hi) {
    u32 r;
    asm("v_cvt_pk_bf16_f32 %0, %1, %2" : "=v"(r) : "v"(lo), "v"(hi));
    return r;
}

// ---------------------------------------------------------------------------
// LayerNorm + split to bf16 hi/lo. One wave per row of 512. Block = 4 rows.
// ---------------------------------------------------------------------------
__global__ __launch_bounds__(256) void ln_split_kernel(
    const float* __restrict__ X, const float* __restrict__ G, const float* __restrict__ Bt,
    u16* __restrict__ oh, u16* __restrict__ ol)
{
    int row  = blockIdx.x * 4 + (threadIdx.x >> 6);
    int lane = threadIdx.x & 63;
    const float4* xr = (const float4*)(X + (size_t)row * DMODEL);
    float4 a = xr[lane * 2], b = xr[lane * 2 + 1];
    float vv[8] = {a.x, a.y, a.z, a.w, b.x, b.y, b.z, b.w};
    float s = 0.f;
#pragma unroll
    for (int i = 0; i < 8; i++) s += vv[i];
#pragma unroll
    for (int o = 32; o; o >>= 1) s += __shfl_xor(s, o);
    float mu = s * (1.0f / DMODEL);
    float vs = 0.f;
#pragma unroll
    for (int i = 0; i < 8; i++) { float d = vv[i] - mu; vs += d * d; }
#pragma unroll
    for (int o = 32; o; o >>= 1) vs += __shfl_xor(vs, o);
    float rstd = rsqrtf(vs * (1.0f / DMODEL) + LN_EPS);

    const float4* g4 = (const float4*)G;
    const float4* b4 = (const float4*)Bt;
    float4 g0 = g4[lane * 2], g1 = g4[lane * 2 + 1];
    float4 c0 = b4[lane * 2], c1 = b4[lane * 2 + 1];
    float gg[8] = {g0.x, g0.y, g0.z, g0.w, g1.x, g1.y, g1.z, g1.w};
    float cc[8] = {c0.x, c0.y, c0.z, c0.w, c1.x, c1.y, c1.z, c1.w};

    s16x8 vh, vl;
#pragma unroll
    for (int i = 0; i < 8; i++) {
        float t = (vv[i] - mu) * rstd * gg[i] + cc[i];
        u16 h = f2bf(t);
        vh[i] = (short)h;
        vl[i] = (short)f2bf(t - bf2f(h));
    }
    size_t o0 = (size_t)row * DMODEL + lane * 8;
    *(s16x8*)(oh + o0) = vh;
    *(s16x8*)(ol + o0) = vl;
}

// ---------------------------------------------------------------------------
// Weight transpose + split, all 4 weights in one launch (blockIdx.y = which)
// ---------------------------------------------------------------------------
__global__ __launch_bounds__(256) void wsplit_kernel(
    const float* __restrict__ W0, const float* __restrict__ W1,
    const float* __restrict__ W2, const float* __restrict__ W3,
    u16* __restrict__ t0, u16* __restrict__ t1)
{
    int which = blockIdx.y;
    const float* W = which == 0 ? W0 : which == 1 ? W1 : which == 2 ? W2 : W3;
    u16* th = t0 + (size_t)which * 2 * 262144;
    u16* tl = th + 262144;
    (void)t1;
    int idx = blockIdx.x * 256 + threadIdx.x;     // idx = n*512 + k
    int n = idx >> 9, k = idx & 511;
    float v = W[(size_t)k * 512 + n];
    u16 h = f2bf(v);
    th[idx] = h;
    tl[idx] = f2bf(v - bf2f(h));
}

// ---------------------------------------------------------------------------
// Split-bf16 GEMM (unchanged; passes).
// ---------------------------------------------------------------------------
template<int MODE>
__global__ __launch_bounds__(256) void gemm_split(
    const u16* __restrict__ Ah, const u16* __restrict__ Al,
    const u16* __restrict__ Bh, const u16* __restrict__ Bl,
    void* __restrict__ out0, void* __restrict__ out1,
    const float* __restrict__ bias, float scl)
{
    constexpr int K  = 512;
    constexpr int LS = 72;
    __shared__ u16 lA[2][64][LS];
    __shared__ u16 lB[2][64][LS];

    int bm = blockIdx.x, bn = blockIdx.y;
    int tid = threadIdx.x, lane = tid & 63, wv = tid >> 6;
    int wm = (wv >> 1) * 32, wn = (wv & 1) * 32;
    int srow = tid >> 3, scol = (tid & 7) * 8;
    const size_t aoff0 = ((size_t)(bm * 64 + srow)) * K + scol;
    const size_t aoff1 = ((size_t)(bm * 64 + srow + 32)) * K + scol;
    const size_t boff0 = ((size_t)(bn * 64 + srow)) * K + scol;
    const size_t boff1 = ((size_t)(bn * 64 + srow + 32)) * K + scol;

    f32x4 acc[2][2] = {};

    for (int k0 = 0; k0 < K; k0 += 64) {
        *(int4*)&lA[0][srow][scol]      = *(const int4*)(Ah + aoff0 + k0);
        *(int4*)&lA[0][srow + 32][scol] = *(const int4*)(Ah + aoff1 + k0);
        *(int4*)&lA[1][srow][scol]      = *(const int4*)(Al + aoff0 + k0);
        *(int4*)&lA[1][srow + 32][scol] = *(const int4*)(Al + aoff1 + k0);
        *(int4*)&lB[0][srow][scol]      = *(const int4*)(Bh + boff0 + k0);
        *(int4*)&lB[0][srow + 32][scol] = *(const int4*)(Bh + boff1 + k0);
        *(int4*)&lB[1][srow][scol]      = *(const int4*)(Bl + boff0 + k0);
        *(int4*)&lB[1][srow + 32][scol] = *(const int4*)(Bl + boff1 + k0);
        __syncthreads();
        int fr = lane & 15, fg = (lane >> 4) * 8;
#pragma unroll
        for (int kk = 0; kk < 64; kk += 32) {
            s16x8 ah[2], al[2], bh[2], bl[2];
#pragma unroll
            for (int m_ = 0; m_ < 2; m_++) {
                ah[m_] = *(const s16x8*)&lA[0][wm + m_ * 16 + fr][kk + fg];
                al[m_] = *(const s16x8*)&lA[1][wm + m_ * 16 + fr][kk + fg];
            }
#pragma unroll
            for (int n_ = 0; n_ < 2; n_++) {
                bh[n_] = *(const s16x8*)&lB[0][wn + n_ * 16 + fr][kk + fg];
                bl[n_] = *(const s16x8*)&lB[1][wn + n_ * 16 + fr][kk + fg];
            }
#pragma unroll
            for (int m_ = 0; m_ < 2; m_++)
#pragma unroll
                for (int n_ = 0; n_ < 2; n_++) {
                    acc[m_][n_] = mfma16(ah[m_], bh[n_], acc[m_][n_]);
                    acc[m_][n_] = mfma16(ah[m_], bl[n_], acc[m_][n_]);
                    acc[m_][n_] = mfma16(al[m_], bh[n_], acc[m_][n_]);
                }
        }
        __syncthreads();
    }

    int fr = lane & 15, fq = lane >> 4;
#pragma unroll
    for (int m_ = 0; m_ < 2; m_++)
#pragma unroll
        for (int n_ = 0; n_ < 2; n_++)
#pragma unroll
            for (int r = 0; r < 4; r++) {
                int gm = bm * 64 + wm + m_ * 16 + fq * 4 + r;
                int gn = bn * 64 + wn + n_ * 16 + fr;
                float v = acc[m_][n_][r];
                if (MODE == 0) {
                    v *= scl;
                    int b_ = gm >> 11, s_ = gm & 2047, h_ = gn >> 6, d_ = gn & 63;
                    size_t adr = (((size_t)(b_ * NH + h_)) * SKV + s_) * DH + d_;
                    u16 hv = f2bf(v);
                    ((u16*)out0)[adr] = hv;
                    ((u16*)out1)[adr] = f2bf(v - bf2f(hv));
                } else if (MODE == 1) {
                    int b_ = gm >> 11, s_ = gm & 2047, h_ = gn >> 6, d_ = gn & 63;
                    size_t adr = (((size_t)(b_ * NH + h_)) * DH + d_) * SKV + s_;
                    ((u16*)out0)[adr] = f2bf(v);
                } else {
                    v += bias[gn];
                    ((float*)out0)[(size_t)gm * DMODEL + gn] = v;
                }
            }
}

// ---------------------------------------------------------------------------
// Streaming attention (R7 geometry/body) with SPLIT MFMA CHAINS.
// R14 theory: all prior variants shared an 8-deep dependent MFMA chain in
// QK^T (a2). At ~100-150cy MFMA result latency and 2-4 waves/SIMD, that
// chain is the invariant ~3300cy/tile slot. Split into 3 independent
// 4-deep chains (a1=kh*qh, a2=kh*ql, a3=kl*qh), summed at the end.
// One block = one 32-q-row tile, 4 waves; wave w owns kv quarter.
//
// Layouts (mfma_f32_32x32x16_bf16, measured m74/m101):
//   A/B frag: row(col) = lane&31, k = 8*(lane>>5) + j, j=0..7
//   C:        col = lane&31,     row = (r&3) + 8*(r>>2) + 4*(lane>>5)
// NOTE: swapped QK^T => q lane-local; attn rows live ACROSS lanes => LDS
// transpose required for coalesced attn stores (round-8 lesson).
// ---------------------------------------------------------------------------
__global__ __launch_bounds__(256, 3) void attn_kernel(
    const u16* __restrict__ Qh, const u16* __restrict__ Ql,
    const u16* __restrict__ Kh, const u16* __restrict__ Kl,
    const u16* __restrict__ VT,
    float* __restrict__ attn, u16* __restrict__ ch, u16* __restrict__ cl)
{
    __shared__ float R[4][2112];       // per-wave: 2 transpose bufs (2x1056) / PV partials (2048)
    __shared__ float rs[4][32];
    int tid = threadIdx.x, lane = tid & 63, wid = tid >> 6;
    int h  = lane >> 5;
    int ql = lane & 31;
    int off = 8 * h;

    // XCD-chunked bijective swizzle: 2048 blocks, 8 XCDs x 256; 4 bh per XCD
    int vb = (blockIdx.x & 7) * 256 + (blockIdx.x >> 3);
    int bh = vb >> 6;
    int qt = vb & 63;
    int q0 = qt * 32;
    const size_t base = (size_t)bh * (SKV * DH);
    int kt0 = wid * 16;

    // ---- Q B-fragments (hi/lo): Q[q0+ql][16c + 8h + 0..7] ----
    s16x8 qfh[4], qfl[4];
    {
        const u16* qp  = Qh + base + ((size_t)(q0 + ql)) * DH + off;
        const u16* qlp = Ql + base + ((size_t)(q0 + ql)) * DH + off;
#pragma unroll
        for (int c = 0; c < 4; c++) {
            qfh[c] = *(const s16x8*)(qp + c * 16);
            qfl[c] = *(const s16x8*)(qlp + c * 16);
        }
    }

    // ---- pass 1: partial rowsum of exp(S); 3 independent 4-deep chains ----
    float rsum0 = 0.f, rsum1 = 0.f;
    for (int kt = kt0; kt < kt0 + 16; kt++) {
        size_t kb = base + ((size_t)(kt * 32 + ql)) * DH + off;
        s16x8 kh[4], kl[4];
#pragma unroll
        for (int c = 0; c < 4; c++) {
            kh[c] = *(const s16x8*)(Kh + kb + c * 16);
            kl[c] = *(const s16x8*)(Kl + kb + c * 16);
        }
        f32x16 a1 = 0, a2 = 0, a3 = 0;
#pragma unroll
        for (int c = 0; c < 4; c++) a1 = mfma32(kh[c], qfh[c], a1);
#pragma unroll
        for (int c = 0; c < 4; c++) a2 = mfma32(kh[c], qfl[c], a2);
#pragma unroll
        for (int c = 0; c < 4; c++) a3 = mfma32(kl[c], qfh[c], a3);
        f32x16 acc = (a1 + a2) + a3;
#pragma unroll
        for (int r = 0; r < 16; r += 2) {
            rsum0 += __expf(acc[r]);
            rsum1 += __expf(acc[r + 1]);
        }
    }
    float rsum = rsum0 + rsum1;
    rsum += __shfl_xor(rsum, 32);
    if (lane < 32) rs[wid][ql] = rsum;
    __syncthreads();
    float inv_l = 1.0f / (rs[0][ql] + rs[1][ql] + rs[2][ql] + rs[3][ql]);

    // ---- pass 2: K prefetched one tile ahead; stores issued last ----
    f32x16 pv0 = 0, pv1 = 0;
    const u16* vbase = VT + (size_t)bh * (DH * SKV) + (size_t)ql * SKV + off;

    s16x8 kA[4], klA[4];               // current tile's K frags (loaded last iter)
    {
        size_t kb = base + ((size_t)(kt0 * 32 + ql)) * DH + off;
#pragma unroll
        for (int c = 0; c < 4; c++) {
            kA[c]  = *(const s16x8*)(Kh + kb + c * 16);
            klA[c] = *(const s16x8*)(Kl + kb + c * 16);
        }
    }

    for (int i = 0; i < 16; i++) {
        int kt = kt0 + i;
        // --- issue this tile's V loads early (before any stores this body) ---
        const u16* vp = vbase + kt * 32;
        s16x8 v00 = *(const s16x8*)(vp);
        s16x8 v01 = *(const s16x8*)(vp + 16);
        s16x8 v10 = *(const s16x8*)(vp + (size_t)32 * SKV);
        s16x8 v11 = *(const s16x8*)(vp + (size_t)32 * SKV + 16);
        // --- issue next tile's K prefetch ---
        s16x8 kB[4], klB[4];
        if (i + 1 < 16) {
            size_t kb = base + ((size_t)((kt + 1) * 32 + ql)) * DH + off;
#pragma unroll
            for (int c = 0; c < 4; c++) {
                kB[c]  = *(const s16x8*)(Kh + kb + c * 16);
                klB[c] = *(const s16x8*)(Kl + kb + c * 16);
            }
        }
        // --- QK^T: 3 independent 4-deep chains ---
        f32x16 a1 = 0, a2 = 0, a3 = 0;
#pragma unroll
        for (int c = 0; c < 4; c++) a1 = mfma32(kA[c], qfh[c], a1);
#pragma unroll
        for (int c = 0; c < 4; c++) a2 = mfma32(kA[c], qfl[c], a2);
#pragma unroll
        for (int c = 0; c < 4; c++) a3 = mfma32(klA[c], qfh[c], a3);
        f32x16 acc = (a1 + a2) + a3;
#pragma unroll
        for (int r = 0; r < 16; r++) acc[r] = __expf(acc[r]) * inv_l;

        // --- PV: pack to bf16 + permlane -> B-frags ---
        u32 O0[4], O1[4];
#pragma unroll
        for (int g = 0; g < 4; g++) {
            O0[g] = cvtpk(acc[4 * g + 0], acc[4 * g + 1]);
            O1[g] = cvtpk(acc[4 * g + 2], acc[4 * g + 3]);
        }
        {
            u32 a = O0[0], b = O0[1], c = O1[0], d = O1[1];
            asm("v_permlane32_swap_b32 %0, %1" : "+v"(a), "+v"(b));
            asm("v_permlane32_swap_b32 %0, %1" : "+v"(c), "+v"(d));
            uint4 w = {a, c, b, d};
            s16x8 bf = __builtin_bit_cast(s16x8, w);
            pv0 = mfma32(v00, bf, pv0);
            pv1 = mfma32(v10, bf, pv1);
        }
        {
            u32 a = O0[2], b = O0[3], c = O1[2], d = O1[3];
            asm("v_permlane32_swap_b32 %0, %1" : "+v"(a), "+v"(b));
            asm("v_permlane32_swap_b32 %0, %1" : "+v"(c), "+v"(d));
            uint4 w = {a, c, b, d};
            s16x8 bf = __builtin_bit_cast(s16x8, w);
            pv0 = mfma32(v01, bf, pv0);
            pv1 = mfma32(v11, bf, pv1);
        }

        // --- LDS transpose (double-buffered by parity) ---
        float* buf = &R[wid][(i & 1) * 1056];
#pragma unroll
        for (int r = 0; r < 16; r++)
            buf[ql * 33 + (r & 3) + 8 * (r >> 2) + 4 * h] = acc[r];

        // --- attn burst: nontemporal, issued last in the body ---
#pragma unroll
        for (int p = 0; p < 4; p++) {
            int q = p * 8 + (lane >> 3), j4 = (lane & 7) * 4;
            f32x4 o;
            o.x = buf[q * 33 + j4 + 0];
            o.y = buf[q * 33 + j4 + 1];
            o.z = buf[q * 33 + j4 + 2];
            o.w = buf[q * 33 + j4 + 3];
            __builtin_nontemporal_store(o,
                (f32x4*)&attn[((size_t)(bh * SQ + q0 + q)) * SKV + kt * 32 + j4]);
        }

#pragma unroll
        for (int c = 0; c < 4; c++) { kA[c] = kB[c]; klA[c] = klB[c]; }
    }

    // ---- write PV partials to own LDS region ----
#pragma unroll
    for (int r = 0; r < 16; r++) {
        R[wid][r * 64 + lane]        = pv0[r];
        R[wid][1024 + r * 64 + lane] = pv1[r];
    }
    __syncthreads();

    // ---- waves 0,1 reduce 4 partials for d-half X=wid and store ctx ----
    if (wid < 2) {
        int X = wid;
        float s[16];
#pragma unroll
        for (int r = 0; r < 16; r++)
            s[r] = R[0][X * 1024 + r * 64 + lane] + R[1][X * 1024 + r * 64 + lane]
                 + R[2][X * 1024 + r * 64 + lane] + R[3][X * 1024 + r * 64 + lane];
        int b_ = bh >> 3, hh = bh & 7;
        size_t rowa = ((size_t)(b_ * SQ + q0 + ql)) * DMODEL + hh * 64 + X * 32 + 4 * h;
#pragma unroll
        for (int g = 0; g < 4; g++) {
            u16 hv[4], lv[4];
#pragma unroll
            for (int i = 0; i < 4; i++) {
                float v = s[4 * g + i];
                hv[i] = f2bf(v);
                lv[i] = f2bf(v - bf2f(hv[i]));
            }
            *(ushort4*)(ch + rowa + 8 * g) = *(ushort4*)hv;
            *(ushort4*)(cl + rowa + 8 * g) = *(ushort4*)lv;
        }
    }
}

// ---------------------------------------------------------------------------
extern "C" void kernel_launch(void* const* d_in, const int* in_sizes, int n_in,
                              void* d_out, int out_size, void* d_ws, size_t ws_size,
                              hipStream_t stream)
{
    const float* x   = (const float*)d_in[0];
    const float* y   = (const float*)d_in[1];
    const float* lqg = (const float*)d_in[2];
    const float* lqb = (const float*)d_in[3];
    const float* lkg = (const float*)d_in[4];
    const float* lkb = (const float*)d_in[5];
    const float* Wq  = (const float*)d_in[6];
    const float* Wk  = (const float*)d_in[7];
    const float* Wv  = (const float*)d_in[8];
    const float* Wo  = (const float*)d_in[9];
    const float* bo  = (const float*)d_in[10];

    char* ws = (char*)d_ws;
    size_t off = 0;
    auto alloc = [&](size_t nelem) -> u16* {
        u16* p = (u16*)(ws + off);
        off += (nelem * 2 + 255) & ~(size_t)255;
        return p;
    };
    const size_t NROW = (size_t)MROWS * DMODEL;
    u16* xnh = alloc(NROW);  u16* xnl = alloc(NROW);
    u16* ynh = alloc(NROW);  u16* ynl = alloc(NROW);
    u16* wbase = alloc(4 * 2 * 262144);
    u16* wqh = wbase + 0 * 2 * 262144; u16* wql = wqh + 262144;
    u16* wkh = wbase + 1 * 2 * 262144; u16* wkl = wkh + 262144;
    u16* wvh = wbase + 2 * 2 * 262144; u16* wvl = wvh + 262144;
    u16* woh = wbase + 3 * 2 * 262144; u16* wol = woh + 262144;
    u16* qh_ = alloc(NROW);  u16* ql_ = alloc(NROW);
    u16* kh_ = alloc(NROW);  u16* kl_ = alloc(NROW);
    u16* vt_ = alloc(NROW);
    u16* cth = alloc(NROW);  u16* ctl = alloc(NROW);

    float* outp  = (float*)d_out;
    float* attnp = outp + (size_t)MROWS * DMODEL;

    ln_split_kernel<<<MROWS / 4, 256, 0, stream>>>(x, lqg, lqb, xnh, xnl);
    ln_split_kernel<<<MROWS / 4, 256, 0, stream>>>(y, lkg, lkb, ynh, ynl);
    wsplit_kernel<<<dim3(1024, 4), 256, 0, stream>>>(Wq, Wk, Wv, Wo, wbase, nullptr);

    dim3 gg(MROWS / 64, 512 / 64);
    gemm_split<0><<<gg, 256, 0, stream>>>(xnh, xnl, wqh, wql, qh_, ql_, nullptr, 0.125f);
    gemm_split<0><<<gg, 256, 0, stream>>>(ynh, ynl, wkh, wkl, kh_, kl_, nullptr, 1.0f);
    gemm_split<1><<<gg, 256, 0, stream>>>(ynh, ynl, wvh, wvl, vt_, nullptr, nullptr, 1.0f);

    attn_kernel<<<2048, 256, 0, stream>>>(qh_, ql_, kh_, kl_, vt_, attnp, cth, ctl);

    gemm_split<2><<<gg, 256, 0, stream>>>(cth, ctl, woh, wol, (void*)outp, nullptr, bo, 1.0f);
}

// Round 15
// 297.645 us; speedup vs baseline: 1.7377x; 1.3819x over previous
//
#include <hip/hip_runtime.h>

typedef float f32x4 __attribute__((ext_vector_type(4)));
typedef float f32x16 __attribute__((ext_vector_type(16)));
typedef __bf16 bf16x8 __attribute__((ext_vector_type(8)));
typedef short s16x8 __attribute__((ext_vector_type(8)));
typedef unsigned short u16;
typedef unsigned int u32;

#define DEV static __device__ __forceinline__

constexpr int BATCH = 4;
constexpr int SQ    = 2048;
constexpr int SKV   = 2048;
constexpr int DMODEL= 512;
constexpr int NH    = 8;
constexpr int DH    = 64;
constexpr int MROWS = BATCH * SQ;      // 8192
constexpr float LN_EPS = 1e-5f;

DEV u16 f2bf(float f) {
    unsigned u = __builtin_bit_cast(unsigned, f);
    unsigned r = (u + 0x7FFFu + ((u >> 16) & 1u)) >> 16;
    return (u16)r;
}
DEV float bf2f(u16 h) { return __builtin_bit_cast(float, ((unsigned)h) << 16); }

DEV f32x4 mfma16(s16x8 a, s16x8 b, f32x4 c) {
    return __builtin_amdgcn_mfma_f32_16x16x32_bf16(
        __builtin_bit_cast(bf16x8, a), __builtin_bit_cast(bf16x8, b), c, 0, 0, 0);
}
DEV f32x16 mfma32(s16x8 a, s16x8 b, f32x16 c) {
    return __builtin_amdgcn_mfma_f32_32x32x16_bf16(
        __builtin_bit_cast(bf16x8, a), __builtin_bit_cast(bf16x8, b), c, 0, 0, 0);
}
DEV u32 cvtpk(float lo, float hi) {
    u32 r;
    asm("v_cvt_pk_bf16_f32 %0, %1, %2" : "=v"(r) : "v"(lo), "v"(hi));
    return r;
}

// ---------------------------------------------------------------------------
// LayerNorm + split to bf16 hi/lo. One wave per row of 512. Block = 4 rows.
// (Split retained for the projection GEMMs' accuracy.)
// ---------------------------------------------------------------------------
__global__ __launch_bounds__(256) void ln_split_kernel(
    const float* __restrict__ X, const float* __restrict__ G, const float* __restrict__ Bt,
    u16* __restrict__ oh, u16* __restrict__ ol)
{
    int row  = blockIdx.x * 4 + (threadIdx.x >> 6);
    int lane = threadIdx.x & 63;
    const float4* xr = (const float4*)(X + (size_t)row * DMODEL);
    float4 a = xr[lane * 2], b = xr[lane * 2 + 1];
    float vv[8] = {a.x, a.y, a.z, a.w, b.x, b.y, b.z, b.w};
    float s = 0.f;
#pragma unroll
    for (int i = 0; i < 8; i++) s += vv[i];
#pragma unroll
    for (int o = 32; o; o >>= 1) s += __shfl_xor(s, o);
    float mu = s * (1.0f / DMODEL);
    float vs = 0.f;
#pragma unroll
    for (int i = 0; i < 8; i++) { float d = vv[i] - mu; vs += d * d; }
#pragma unroll
    for (int o = 32; o; o >>= 1) vs += __shfl_xor(vs, o);
    float rstd = rsqrtf(vs * (1.0f / DMODEL) + LN_EPS);

    const float4* g4 = (const float4*)G;
    const float4* b4 = (const float4*)Bt;
    float4 g0 = g4[lane * 2], g1 = g4[lane * 2 + 1];
    float4 c0 = b4[lane * 2], c1 = b4[lane * 2 + 1];
    float gg[8] = {g0.x, g0.y, g0.z, g0.w, g1.x, g1.y, g1.z, g1.w};
    float cc[8] = {c0.x, c0.y, c0.z, c0.w, c1.x, c1.y, c1.z, c1.w};

    s16x8 vh, vl;
#pragma unroll
    for (int i = 0; i < 8; i++) {
        float t = (vv[i] - mu) * rstd * gg[i] + cc[i];
        u16 h = f2bf(t);
        vh[i] = (short)h;
        vl[i] = (short)f2bf(t - bf2f(h));
    }
    size_t o0 = (size_t)row * DMODEL + lane * 8;
    *(s16x8*)(oh + o0) = vh;
    *(s16x8*)(ol + o0) = vl;
}

// ---------------------------------------------------------------------------
// Weight transpose + split, all 4 weights in one launch (blockIdx.y = which)
// ---------------------------------------------------------------------------
__global__ __launch_bounds__(256) void wsplit_kernel(
    const float* __restrict__ W0, const float* __restrict__ W1,
    const float* __restrict__ W2, const float* __restrict__ W3,
    u16* __restrict__ t0, u16* __restrict__ t1)
{
    int which = blockIdx.y;
    const float* W = which == 0 ? W0 : which == 1 ? W1 : which == 2 ? W2 : W3;
    u16* th = t0 + (size_t)which * 2 * 262144;
    u16* tl = th + 262144;
    (void)t1;
    int idx = blockIdx.x * 256 + threadIdx.x;     // idx = n*512 + k
    int n = idx >> 9, k = idx & 511;
    float v = W[(size_t)k * 512 + n];
    u16 h = f2bf(v);
    th[idx] = h;
    tl[idx] = f2bf(v - bf2f(h));
}

// ---------------------------------------------------------------------------
// Split-bf16 GEMM. MODE 0: split hi/lo out (unused now for Q/K but kept),
// MODE 1: V^T bf16, MODE 2: fp32+bias, MODE 3: bf16-only out at (b,h,s,d).
// ---------------------------------------------------------------------------
template<int MODE>
__global__ __launch_bounds__(256) void gemm_split(
    const u16* __restrict__ Ah, const u16* __restrict__ Al,
    const u16* __restrict__ Bh, const u16* __restrict__ Bl,
    void* __restrict__ out0, void* __restrict__ out1,
    const float* __restrict__ bias, float scl)
{
    constexpr int K  = 512;
    constexpr int LS = 72;
    __shared__ u16 lA[2][64][LS];
    __shared__ u16 lB[2][64][LS];

    int bm = blockIdx.x, bn = blockIdx.y;
    int tid = threadIdx.x, lane = tid & 63, wv = tid >> 6;
    int wm = (wv >> 1) * 32, wn = (wv & 1) * 32;
    int srow = tid >> 3, scol = (tid & 7) * 8;
    const size_t aoff0 = ((size_t)(bm * 64 + srow)) * K + scol;
    const size_t aoff1 = ((size_t)(bm * 64 + srow + 32)) * K + scol;
    const size_t boff0 = ((size_t)(bn * 64 + srow)) * K + scol;
    const size_t boff1 = ((size_t)(bn * 64 + srow + 32)) * K + scol;

    f32x4 acc[2][2] = {};

    for (int k0 = 0; k0 < K; k0 += 64) {
        *(int4*)&lA[0][srow][scol]      = *(const int4*)(Ah + aoff0 + k0);
        *(int4*)&lA[0][srow + 32][scol] = *(const int4*)(Ah + aoff1 + k0);
        *(int4*)&lA[1][srow][scol]      = *(const int4*)(Al + aoff0 + k0);
        *(int4*)&lA[1][srow + 32][scol] = *(const int4*)(Al + aoff1 + k0);
        *(int4*)&lB[0][srow][scol]      = *(const int4*)(Bh + boff0 + k0);
        *(int4*)&lB[0][srow + 32][scol] = *(const int4*)(Bh + boff1 + k0);
        *(int4*)&lB[1][srow][scol]      = *(const int4*)(Bl + boff0 + k0);
        *(int4*)&lB[1][srow + 32][scol] = *(const int4*)(Bl + boff1 + k0);
        __syncthreads();
        int fr = lane & 15, fg = (lane >> 4) * 8;
#pragma unroll
        for (int kk = 0; kk < 64; kk += 32) {
            s16x8 ah[2], al[2], bh[2], bl[2];
#pragma unroll
            for (int m_ = 0; m_ < 2; m_++) {
                ah[m_] = *(const s16x8*)&lA[0][wm + m_ * 16 + fr][kk + fg];
                al[m_] = *(const s16x8*)&lA[1][wm + m_ * 16 + fr][kk + fg];
            }
#pragma unroll
            for (int n_ = 0; n_ < 2; n_++) {
                bh[n_] = *(const s16x8*)&lB[0][wn + n_ * 16 + fr][kk + fg];
                bl[n_] = *(const s16x8*)&lB[1][wn + n_ * 16 + fr][kk + fg];
            }
#pragma unroll
            for (int m_ = 0; m_ < 2; m_++)
#pragma unroll
                for (int n_ = 0; n_ < 2; n_++) {
                    acc[m_][n_] = mfma16(ah[m_], bh[n_], acc[m_][n_]);
                    acc[m_][n_] = mfma16(ah[m_], bl[n_], acc[m_][n_]);
                    acc[m_][n_] = mfma16(al[m_], bh[n_], acc[m_][n_]);
                }
        }
        __syncthreads();
    }

    int fr = lane & 15, fq = lane >> 4;
#pragma unroll
    for (int m_ = 0; m_ < 2; m_++)
#pragma unroll
        for (int n_ = 0; n_ < 2; n_++)
#pragma unroll
            for (int r = 0; r < 4; r++) {
                int gm = bm * 64 + wm + m_ * 16 + fq * 4 + r;
                int gn = bn * 64 + wn + n_ * 16 + fr;
                float v = acc[m_][n_][r];
                if (MODE == 0) {
                    v *= scl;
                    int b_ = gm >> 11, s_ = gm & 2047, h_ = gn >> 6, d_ = gn & 63;
                    size_t adr = (((size_t)(b_ * NH + h_)) * SKV + s_) * DH + d_;
                    u16 hv = f2bf(v);
                    ((u16*)out0)[adr] = hv;
                    ((u16*)out1)[adr] = f2bf(v - bf2f(hv));
                } else if (MODE == 1) {
                    int b_ = gm >> 11, s_ = gm & 2047, h_ = gn >> 6, d_ = gn & 63;
                    size_t adr = (((size_t)(b_ * NH + h_)) * DH + d_) * SKV + s_;
                    ((u16*)out0)[adr] = f2bf(v);
                } else if (MODE == 3) {
                    v *= scl;
                    int b_ = gm >> 11, s_ = gm & 2047, h_ = gn >> 6, d_ = gn & 63;
                    size_t adr = (((size_t)(b_ * NH + h_)) * SKV + s_) * DH + d_;
                    ((u16*)out0)[adr] = f2bf(v);
                } else {
                    v += bias[gn];
                    ((float*)out0)[(size_t)gm * DMODEL + gn] = v;
                }
            }
}

// ---------------------------------------------------------------------------
// Streaming attention, PLAIN-BF16 QK^T (R15).
// Error analysis: bf16 logit error RMS ~2.5e-3 -> attn error ~1e-4 abs,
// 60x under the 6.09e-3 threshold and below the existing P->bf16 rounding.
// Per tile-op MFMA 28 -> 12; pass 1 shrinks to ~1/3 of loop -> store duty up.
// One block = one 32-q-row tile, 4 waves; wave w owns kv quarter (16 tiles).
//
// Layouts (mfma_f32_32x32x16_bf16, measured m74/m101):
//   A/B frag: row(col) = lane&31, k = 8*(lane>>5) + j, j=0..7
//   C:        col = lane&31,     row = (r&3) + 8*(r>>2) + 4*(lane>>5)
// NOTE: swapped QK^T => q lane-local; attn rows live ACROSS lanes => LDS
// transpose required for coalesced attn stores (round-8 lesson).
// ---------------------------------------------------------------------------
__global__ __launch_bounds__(256, 3) void attn_kernel(
    const u16* __restrict__ Qh, const u16* __restrict__ Kh,
    const u16* __restrict__ VT,
    float* __restrict__ attn, u16* __restrict__ ch, u16* __restrict__ cl)
{
    __shared__ float R[4][2112];       // per-wave: 2 transpose bufs (2x1056) / PV partials (2048)
    __shared__ float rs[4][32];
    int tid = threadIdx.x, lane = tid & 63, wid = tid >> 6;
    int h  = lane >> 5;
    int ql = lane & 31;
    int off = 8 * h;

    // XCD-chunked bijective swizzle: 2048 blocks, 8 XCDs x 256; 4 bh per XCD
    int vb = (blockIdx.x & 7) * 256 + (blockIdx.x >> 3);
    int bh = vb >> 6;
    int qt = vb & 63;
    int q0 = qt * 32;
    const size_t base = (size_t)bh * (SKV * DH);
    int kt0 = wid * 16;

    // ---- Q B-fragments: Q[q0+ql][16c + 8h + 0..7] ----
    s16x8 qf[4];
    {
        const u16* qp = Qh + base + ((size_t)(q0 + ql)) * DH + off;
#pragma unroll
        for (int c = 0; c < 4; c++) qf[c] = *(const s16x8*)(qp + c * 16);
    }

    // ---- pass 1: partial rowsum of exp(S) ----
    float rsum0 = 0.f, rsum1 = 0.f;
    for (int kt = kt0; kt < kt0 + 16; kt++) {
        size_t kb = base + ((size_t)(kt * 32 + ql)) * DH + off;
        s16x8 kh[4];
#pragma unroll
        for (int c = 0; c < 4; c++) kh[c] = *(const s16x8*)(Kh + kb + c * 16);
        f32x16 a1 = 0;
#pragma unroll
        for (int c = 0; c < 4; c++) a1 = mfma32(kh[c], qf[c], a1);
#pragma unroll
        for (int r = 0; r < 16; r += 2) {
            rsum0 += __expf(a1[r]);
            rsum1 += __expf(a1[r + 1]);
        }
    }
    float rsum = rsum0 + rsum1;
    rsum += __shfl_xor(rsum, 32);
    if (lane < 32) rs[wid][ql] = rsum;
    __syncthreads();
    float inv_l = 1.0f / (rs[0][ql] + rs[1][ql] + rs[2][ql] + rs[3][ql]);

    // ---- pass 2: K prefetched one tile ahead; stores issued last ----
    f32x16 pv0 = 0, pv1 = 0;
    const u16* vbase = VT + (size_t)bh * (DH * SKV) + (size_t)ql * SKV + off;

    s16x8 kA[4];                       // current tile's K frags (loaded last iter)
    {
        size_t kb = base + ((size_t)(kt0 * 32 + ql)) * DH + off;
#pragma unroll
        for (int c = 0; c < 4; c++) kA[c] = *(const s16x8*)(Kh + kb + c * 16);
    }

    for (int i = 0; i < 16; i++) {
        int kt = kt0 + i;
        // --- issue this tile's V loads early (before any stores this body) ---
        const u16* vp = vbase + kt * 32;
        s16x8 v00 = *(const s16x8*)(vp);
        s16x8 v01 = *(const s16x8*)(vp + 16);
        s16x8 v10 = *(const s16x8*)(vp + (size_t)32 * SKV);
        s16x8 v11 = *(const s16x8*)(vp + (size_t)32 * SKV + 16);
        // --- issue next tile's K prefetch ---
        s16x8 kB[4];
        if (i + 1 < 16) {
            size_t kb = base + ((size_t)((kt + 1) * 32 + ql)) * DH + off;
#pragma unroll
            for (int c = 0; c < 4; c++) kB[c] = *(const s16x8*)(Kh + kb + c * 16);
        }
        // --- QK^T from prefetched regs (single 4-deep chain) ---
        f32x16 acc = 0;
#pragma unroll
        for (int c = 0; c < 4; c++) acc = mfma32(kA[c], qf[c], acc);
#pragma unroll
        for (int r = 0; r < 16; r++) acc[r] = __expf(acc[r]) * inv_l;

        // --- PV: pack to bf16 + permlane -> B-frags ---
        u32 O0[4], O1[4];
#pragma unroll
        for (int g = 0; g < 4; g++) {
            O0[g] = cvtpk(acc[4 * g + 0], acc[4 * g + 1]);
            O1[g] = cvtpk(acc[4 * g + 2], acc[4 * g + 3]);
        }
        {
            u32 a = O0[0], b = O0[1], c = O1[0], d = O1[1];
            asm("v_permlane32_swap_b32 %0, %1" : "+v"(a), "+v"(b));
            asm("v_permlane32_swap_b32 %0, %1" : "+v"(c), "+v"(d));
            uint4 w = {a, c, b, d};
            s16x8 bf = __builtin_bit_cast(s16x8, w);
            pv0 = mfma32(v00, bf, pv0);
            pv1 = mfma32(v10, bf, pv1);
        }
        {
            u32 a = O0[2], b = O0[3], c = O1[2], d = O1[3];
            asm("v_permlane32_swap_b32 %0, %1" : "+v"(a), "+v"(b));
            asm("v_permlane32_swap_b32 %0, %1" : "+v"(c), "+v"(d));
            uint4 w = {a, c, b, d};
            s16x8 bf = __builtin_bit_cast(s16x8, w);
            pv0 = mfma32(v01, bf, pv0);
            pv1 = mfma32(v11, bf, pv1);
        }

        // --- LDS transpose (double-buffered by parity) ---
        float* buf = &R[wid][(i & 1) * 1056];
#pragma unroll
        for (int r = 0; r < 16; r++)
            buf[ql * 33 + (r & 3) + 8 * (r >> 2) + 4 * h] = acc[r];

        // --- attn burst: nontemporal, issued last in the body ---
#pragma unroll
        for (int p = 0; p < 4; p++) {
            int q = p * 8 + (lane >> 3), j4 = (lane & 7) * 4;
            f32x4 o;
            o.x = buf[q * 33 + j4 + 0];
            o.y = buf[q * 33 + j4 + 1];
            o.z = buf[q * 33 + j4 + 2];
            o.w = buf[q * 33 + j4 + 3];
            __builtin_nontemporal_store(o,
                (f32x4*)&attn[((size_t)(bh * SQ + q0 + q)) * SKV + kt * 32 + j4]);
        }

#pragma unroll
        for (int c = 0; c < 4; c++) kA[c] = kB[c];
    }

    // ---- write PV partials to own LDS region ----
#pragma unroll
    for (int r = 0; r < 16; r++) {
        R[wid][r * 64 + lane]        = pv0[r];
        R[wid][1024 + r * 64 + lane] = pv1[r];
    }
    __syncthreads();

    // ---- waves 0,1 reduce 4 partials for d-half X=wid and store ctx ----
    if (wid < 2) {
        int X = wid;
        float s[16];
#pragma unroll
        for (int r = 0; r < 16; r++)
            s[r] = R[0][X * 1024 + r * 64 + lane] + R[1][X * 1024 + r * 64 + lane]
                 + R[2][X * 1024 + r * 64 + lane] + R[3][X * 1024 + r * 64 + lane];
        int b_ = bh >> 3, hh = bh & 7;
        size_t rowa = ((size_t)(b_ * SQ + q0 + ql)) * DMODEL + hh * 64 + X * 32 + 4 * h;
#pragma unroll
        for (int g = 0; g < 4; g++) {
            u16 hv[4], lv[4];
#pragma unroll
            for (int i = 0; i < 4; i++) {
                float v = s[4 * g + i];
                hv[i] = f2bf(v);
                lv[i] = f2bf(v - bf2f(hv[i]));
            }
            *(ushort4*)(ch + rowa + 8 * g) = *(ushort4*)hv;
            *(ushort4*)(cl + rowa + 8 * g) = *(ushort4*)lv;
        }
    }
}

// ---------------------------------------------------------------------------
extern "C" void kernel_launch(void* const* d_in, const int* in_sizes, int n_in,
                              void* d_out, int out_size, void* d_ws, size_t ws_size,
                              hipStream_t stream)
{
    const float* x   = (const float*)d_in[0];
    const float* y   = (const float*)d_in[1];
    const float* lqg = (const float*)d_in[2];
    const float* lqb = (const float*)d_in[3];
    const float* lkg = (const float*)d_in[4];
    const float* lkb = (const float*)d_in[5];
    const float* Wq  = (const float*)d_in[6];
    const float* Wk  = (const float*)d_in[7];
    const float* Wv  = (const float*)d_in[8];
    const float* Wo  = (const float*)d_in[9];
    const float* bo  = (const float*)d_in[10];

    char* ws = (char*)d_ws;
    size_t off = 0;
    auto alloc = [&](size_t nelem) -> u16* {
        u16* p = (u16*)(ws + off);
        off += (nelem * 2 + 255) & ~(size_t)255;
        return p;
    };
    const size_t NROW = (size_t)MROWS * DMODEL;
    u16* xnh = alloc(NROW);  u16* xnl = alloc(NROW);
    u16* ynh = alloc(NROW);  u16* ynl = alloc(NROW);
    u16* wbase = alloc(4 * 2 * 262144);
    u16* wqh = wbase + 0 * 2 * 262144; u16* wql = wqh + 262144;
    u16* wkh = wbase + 1 * 2 * 262144; u16* wkl = wkh + 262144;
    u16* wvh = wbase + 2 * 2 * 262144; u16* wvl = wvh + 262144;
    u16* woh = wbase + 3 * 2 * 262144; u16* wol = woh + 262144;
    u16* qh_ = alloc(NROW);
    u16* kh_ = alloc(NROW);
    u16* vt_ = alloc(NROW);
    u16* cth = alloc(NROW);  u16* ctl = alloc(NROW);

    float* outp  = (float*)d_out;
    float* attnp = outp + (size_t)MROWS * DMODEL;

    ln_split_kernel<<<MROWS / 4, 256, 0, stream>>>(x, lqg, lqb, xnh, xnl);
    ln_split_kernel<<<MROWS / 4, 256, 0, stream>>>(y, lkg, lkb, ynh, ynl);
    wsplit_kernel<<<dim3(1024, 4), 256, 0, stream>>>(Wq, Wk, Wv, Wo, wbase, nullptr);

    dim3 gg(MROWS / 64, 512 / 64);
    gemm_split<3><<<gg, 256, 0, stream>>>(xnh, xnl, wqh, wql, qh_, nullptr, nullptr, 0.125f);
    gemm_split<3><<<gg, 256, 0, stream>>>(ynh, ynl, wkh, wkl, kh_, nullptr, nullptr, 1.0f);
    gemm_split<1><<<gg, 256, 0, stream>>>(ynh, ynl, wvh, wvl, vt_, nullptr, nullptr, 1.0f);

    attn_kernel<<<2048, 256, 0, stream>>>(qh_, kh_, vt_, attnp, cth, ctl);

    gemm_split<2><<<gg, 256, 0, stream>>>(cth, ctl, woh, wol, (void*)outp, nullptr, bo, 1.0f);
}

// Round 17
// 276.918 us; speedup vs baseline: 1.8678x; 1.0749x over previous
//
#include <hip/hip_runtime.h>

typedef float f32x4 __attribute__((ext_vector_type(4)));
typedef float f32x16 __attribute__((ext_vector_type(16)));
typedef __bf16 bf16x8 __attribute__((ext_vector_type(8)));
typedef short s16x8 __attribute__((ext_vector_type(8)));
typedef unsigned short u16;
typedef unsigned int u32;

#define DEV static __device__ __forceinline__

constexpr int BATCH = 4;
constexpr int SQ    = 2048;
constexpr int SKV   = 2048;
constexpr int DMODEL= 512;
constexpr int NH    = 8;
constexpr int DH    = 64;
constexpr int MROWS = BATCH * SQ;      // 8192
constexpr float LN_EPS = 1e-5f;

DEV u16 f2bf(float f) {
    unsigned u = __builtin_bit_cast(unsigned, f);
    unsigned r = (u + 0x7FFFu + ((u >> 16) & 1u)) >> 16;
    return (u16)r;
}
DEV float bf2f(u16 h) { return __builtin_bit_cast(float, ((unsigned)h) << 16); }

DEV f32x4 mfma16(s16x8 a, s16x8 b, f32x4 c) {
    return __builtin_amdgcn_mfma_f32_16x16x32_bf16(
        __builtin_bit_cast(bf16x8, a), __builtin_bit_cast(bf16x8, b), c, 0, 0, 0);
}
DEV f32x16 mfma32(s16x8 a, s16x8 b, f32x16 c) {
    return __builtin_amdgcn_mfma_f32_32x32x16_bf16(
        __builtin_bit_cast(bf16x8, a), __builtin_bit_cast(bf16x8, b), c, 0, 0, 0);
}
DEV u32 cvtpk(float lo, float hi) {
    u32 r;
    asm("v_cvt_pk_bf16_f32 %0, %1, %2" : "=v"(r) : "v"(lo), "v"(hi));
    return r;
}

// ---------------------------------------------------------------------------
// LayerNorm + split to bf16 hi/lo. One wave per row of 512. Block = 4 rows.
// (Split retained: Q/K projections stay 3-term for logit accuracy.)
// ---------------------------------------------------------------------------
__global__ __launch_bounds__(256) void ln_split_kernel(
    const float* __restrict__ X, const float* __restrict__ G, const float* __restrict__ Bt,
    u16* __restrict__ oh, u16* __restrict__ ol)
{
    int row  = blockIdx.x * 4 + (threadIdx.x >> 6);
    int lane = threadIdx.x & 63;
    const float4* xr = (const float4*)(X + (size_t)row * DMODEL);
    float4 a = xr[lane * 2], b = xr[lane * 2 + 1];
    float vv[8] = {a.x, a.y, a.z, a.w, b.x, b.y, b.z, b.w};
    float s = 0.f;
#pragma unroll
    for (int i = 0; i < 8; i++) s += vv[i];
#pragma unroll
    for (int o = 32; o; o >>= 1) s += __shfl_xor(s, o);
    float mu = s * (1.0f / DMODEL);
    float vs = 0.f;
#pragma unroll
    for (int i = 0; i < 8; i++) { float d = vv[i] - mu; vs += d * d; }
#pragma unroll
    for (int o = 32; o; o >>= 1) vs += __shfl_xor(vs, o);
    float rstd = rsqrtf(vs * (1.0f / DMODEL) + LN_EPS);

    const float4* g4 = (const float4*)G;
    const float4* b4 = (const float4*)Bt;
    float4 g0 = g4[lane * 2], g1 = g4[lane * 2 + 1];
    float4 c0 = b4[lane * 2], c1 = b4[lane * 2 + 1];
    float gg[8] = {g0.x, g0.y, g0.z, g0.w, g1.x, g1.y, g1.z, g1.w};
    float cc[8] = {c0.x, c0.y, c0.z, c0.w, c1.x, c1.y, c1.z, c1.w};

    s16x8 vh, vl;
#pragma unroll
    for (int i = 0; i < 8; i++) {
        float t = (vv[i] - mu) * rstd * gg[i] + cc[i];
        u16 h = f2bf(t);
        vh[i] = (short)h;
        vl[i] = (short)f2bf(t - bf2f(h));
    }
    size_t o0 = (size_t)row * DMODEL + lane * 8;
    *(s16x8*)(oh + o0) = vh;
    *(s16x8*)(ol + o0) = vl;
}

// ---------------------------------------------------------------------------
// Weight transpose + split, all 4 weights in one launch (blockIdx.y = which)
// ---------------------------------------------------------------------------
__global__ __launch_bounds__(256) void wsplit_kernel(
    const float* __restrict__ W0, const float* __restrict__ W1,
    const float* __restrict__ W2, const float* __restrict__ W3,
    u16* __restrict__ t0, u16* __restrict__ t1)
{
    int which = blockIdx.y;
    const float* W = which == 0 ? W0 : which == 1 ? W1 : which == 2 ? W2 : W3;
    u16* th = t0 + (size_t)which * 2 * 262144;
    u16* tl = th + 262144;
    (void)t1;
    int idx = blockIdx.x * 256 + threadIdx.x;     // idx = n*512 + k
    int n = idx >> 9, k = idx & 511;
    float v = W[(size_t)k * 512 + n];
    u16 h = f2bf(v);
    th[idx] = h;
    tl[idx] = f2bf(v - bf2f(h));
}

// ---------------------------------------------------------------------------
// GEMM. MODE 3: 3-term split, bf16 out at (b,h,s,d), scaled  (Q/K)
//       MODE 5: 1-term, bf16 V^T out at (b,h,d,s)            (V)
//       MODE 4: 1-term, fp32 + bias out                      (out)
// Error budget for 1-term: Dout ~ 0.4%*||ctx||*||Wo_col|| ~ 1e-4 << 6e-3.
// ---------------------------------------------------------------------------
template<int MODE>
__global__ __launch_bounds__(256) void gemm_split(
    const u16* __restrict__ Ah, const u16* __restrict__ Al,
    const u16* __restrict__ Bh, const u16* __restrict__ Bl,
    void* __restrict__ out0, const float* __restrict__ bias, float scl)
{
    constexpr int K  = 512;
    constexpr int LS = 72;
    constexpr bool THREE = (MODE == 3);
    __shared__ u16 lA[2][64][LS];
    __shared__ u16 lB[2][64][LS];

    int bm = blockIdx.x, bn = blockIdx.y;
    int tid = threadIdx.x, lane = tid & 63, wv = tid >> 6;
    int wm = (wv >> 1) * 32, wn = (wv & 1) * 32;
    int srow = tid >> 3, scol = (tid & 7) * 8;
    const size_t aoff0 = ((size_t)(bm * 64 + srow)) * K + scol;
    const size_t aoff1 = ((size_t)(bm * 64 + srow + 32)) * K + scol;
    const size_t boff0 = ((size_t)(bn * 64 + srow)) * K + scol;
    const size_t boff1 = ((size_t)(bn * 64 + srow + 32)) * K + scol;

    f32x4 acc[2][2] = {};

    for (int k0 = 0; k0 < K; k0 += 64) {
        *(int4*)&lA[0][srow][scol]      = *(const int4*)(Ah + aoff0 + k0);
        *(int4*)&lA[0][srow + 32][scol] = *(const int4*)(Ah + aoff1 + k0);
        *(int4*)&lB[0][srow][scol]      = *(const int4*)(Bh + boff0 + k0);
        *(int4*)&lB[0][srow + 32][scol] = *(const int4*)(Bh + boff1 + k0);
        if constexpr (THREE) {
            *(int4*)&lA[1][srow][scol]      = *(const int4*)(Al + aoff0 + k0);
            *(int4*)&lA[1][srow + 32][scol] = *(const int4*)(Al + aoff1 + k0);
            *(int4*)&lB[1][srow][scol]      = *(const int4*)(Bl + boff0 + k0);
            *(int4*)&lB[1][srow + 32][scol] = *(const int4*)(Bl + boff1 + k0);
        }
        __syncthreads();
        int fr = lane & 15, fg = (lane >> 4) * 8;
#pragma unroll
        for (int kk = 0; kk < 64; kk += 32) {
            s16x8 ah[2], bh[2];
#pragma unroll
            for (int m_ = 0; m_ < 2; m_++)
                ah[m_] = *(const s16x8*)&lA[0][wm + m_ * 16 + fr][kk + fg];
#pragma unroll
            for (int n_ = 0; n_ < 2; n_++)
                bh[n_] = *(const s16x8*)&lB[0][wn + n_ * 16 + fr][kk + fg];
            if constexpr (THREE) {
                s16x8 al[2], bl[2];
#pragma unroll
                for (int m_ = 0; m_ < 2; m_++)
                    al[m_] = *(const s16x8*)&lA[1][wm + m_ * 16 + fr][kk + fg];
#pragma unroll
                for (int n_ = 0; n_ < 2; n_++)
                    bl[n_] = *(const s16x8*)&lB[1][wn + n_ * 16 + fr][kk + fg];
#pragma unroll
                for (int m_ = 0; m_ < 2; m_++)
#pragma unroll
                    for (int n_ = 0; n_ < 2; n_++) {
                        acc[m_][n_] = mfma16(ah[m_], bh[n_], acc[m_][n_]);
                        acc[m_][n_] = mfma16(ah[m_], bl[n_], acc[m_][n_]);
                        acc[m_][n_] = mfma16(al[m_], bh[n_], acc[m_][n_]);
                    }
            } else {
#pragma unroll
                for (int m_ = 0; m_ < 2; m_++)
#pragma unroll
                    for (int n_ = 0; n_ < 2; n_++)
                        acc[m_][n_] = mfma16(ah[m_], bh[n_], acc[m_][n_]);
            }
        }
        __syncthreads();
    }

    int fr = lane & 15, fq = lane >> 4;
#pragma unroll
    for (int m_ = 0; m_ < 2; m_++)
#pragma unroll
        for (int n_ = 0; n_ < 2; n_++)
#pragma unroll
            for (int r = 0; r < 4; r++) {
                int gm = bm * 64 + wm + m_ * 16 + fq * 4 + r;
                int gn = bn * 64 + wn + n_ * 16 + fr;
                float v = acc[m_][n_][r];
                if (MODE == 3) {
                    v *= scl;
                    int b_ = gm >> 11, s_ = gm & 2047, h_ = gn >> 6, d_ = gn & 63;
                    size_t adr = (((size_t)(b_ * NH + h_)) * SKV + s_) * DH + d_;
                    ((u16*)out0)[adr] = f2bf(v);
                } else if (MODE == 5) {
                    int b_ = gm >> 11, s_ = gm & 2047, h_ = gn >> 6, d_ = gn & 63;
                    size_t adr = (((size_t)(b_ * NH + h_)) * DH + d_) * SKV + s_;
                    ((u16*)out0)[adr] = f2bf(v);
                } else {
                    v += bias[gn];
                    ((float*)out0)[(size_t)gm * DMODEL + gn] = v;
                }
            }
}

// ---------------------------------------------------------------------------
// Streaming attention (R15 verified body; ctx written single-bf16 only).
// One block = one 32-q-row tile, 4 waves; wave w owns kv quarter (16 tiles).
// Pass 1: rowsum of exp(S). Pass 2: K prefetched one tile ahead, normalized
// P packed to bf16 for PV, attn coalesced via per-wave LDS transpose,
// nontemporal f32x4 stores.
//
// Layouts (mfma_f32_32x32x16_bf16, measured m74/m101):
//   A/B frag: row(col) = lane&31, k = 8*(lane>>5) + j, j=0..7
//   C:        col = lane&31,     row = (r&3) + 8*(r>>2) + 4*(lane>>5)
// NOTE: swapped QK^T => q lane-local; attn rows live ACROSS lanes => LDS
// transpose required for coalesced attn stores (round-8 lesson).
// ---------------------------------------------------------------------------
__global__ __launch_bounds__(256, 3) void attn_kernel(
    const u16* __restrict__ Qh, const u16* __restrict__ Kh,
    const u16* __restrict__ VT,
    float* __restrict__ attn, u16* __restrict__ ch)
{
    __shared__ float R[4][2112];       // per-wave: 2 transpose bufs (2x1056) / PV partials (2048)
    __shared__ float rs[4][32];
    int tid = threadIdx.x, lane = tid & 63, wid = tid >> 6;
    int h  = lane >> 5;
    int ql = lane & 31;
    int off = 8 * h;

    // XCD-chunked bijective swizzle: 2048 blocks, 8 XCDs x 256; 4 bh per XCD
    int vb = (blockIdx.x & 7) * 256 + (blockIdx.x >> 3);
    int bh = vb >> 6;
    int qt = vb & 63;
    int q0 = qt * 32;
    const size_t base = (size_t)bh * (SKV * DH);
    int kt0 = wid * 16;

    // ---- Q B-fragments: Q[q0+ql][16c + 8h + 0..7] ----
    s16x8 qf[4];
    {
        const u16* qp = Qh + base + ((size_t)(q0 + ql)) * DH + off;
#pragma unroll
        for (int c = 0; c < 4; c++) qf[c] = *(const s16x8*)(qp + c * 16);
    }

    // ---- pass 1: partial rowsum of exp(S) ----
    float rsum0 = 0.f, rsum1 = 0.f;
    for (int kt = kt0; kt < kt0 + 16; kt++) {
        size_t kb = base + ((size_t)(kt * 32 + ql)) * DH + off;
        s16x8 kh[4];
#pragma unroll
        for (int c = 0; c < 4; c++) kh[c] = *(const s16x8*)(Kh + kb + c * 16);
        f32x16 a1 = 0;
#pragma unroll
        for (int c = 0; c < 4; c++) a1 = mfma32(kh[c], qf[c], a1);
#pragma unroll
        for (int r = 0; r < 16; r += 2) {
            rsum0 += __expf(a1[r]);
            rsum1 += __expf(a1[r + 1]);
        }
    }
    float rsum = rsum0 + rsum1;
    rsum += __shfl_xor(rsum, 32);
    if (lane < 32) rs[wid][ql] = rsum;
    __syncthreads();
    float inv_l = 1.0f / (rs[0][ql] + rs[1][ql] + rs[2][ql] + rs[3][ql]);

    // ---- pass 2: K prefetched one tile ahead; stores issued last ----
    f32x16 pv0 = 0, pv1 = 0;
    const u16* vbase = VT + (size_t)bh * (DH * SKV) + (size_t)ql * SKV + off;

    s16x8 kA[4];
    {
        size_t kb = base + ((size_t)(kt0 * 32 + ql)) * DH + off;
#pragma unroll
        for (int c = 0; c < 4; c++) kA[c] = *(const s16x8*)(Kh + kb + c * 16);
    }

    for (int i = 0; i < 16; i++) {
        int kt = kt0 + i;
        // --- issue this tile's V loads early (before any stores this body) ---
        const u16* vp = vbase + kt * 32;
        s16x8 v00 = *(const s16x8*)(vp);
        s16x8 v01 = *(const s16x8*)(vp + 16);
        s16x8 v10 = *(const s16x8*)(vp + (size_t)32 * SKV);
        s16x8 v11 = *(const s16x8*)(vp + (size_t)32 * SKV + 16);
        // --- issue next tile's K prefetch ---
        s16x8 kB[4];
        if (i + 1 < 16) {
            size_t kb = base + ((size_t)((kt + 1) * 32 + ql)) * DH + off;
#pragma unroll
            for (int c = 0; c < 4; c++) kB[c] = *(const s16x8*)(Kh + kb + c * 16);
        }
        // --- QK^T from prefetched regs ---
        f32x16 acc = 0;
#pragma unroll
        for (int c = 0; c < 4; c++) acc = mfma32(kA[c], qf[c], acc);
#pragma unroll
        for (int r = 0; r < 16; r++) acc[r] = __expf(acc[r]) * inv_l;

        // --- PV: pack to bf16 + permlane -> B-frags ---
        u32 O0[4], O1[4];
#pragma unroll
        for (int g = 0; g < 4; g++) {
            O0[g] = cvtpk(acc[4 * g + 0], acc[4 * g + 1]);
            O1[g] = cvtpk(acc[4 * g + 2], acc[4 * g + 3]);
        }
        {
            u32 a = O0[0], b = O0[1], c = O1[0], d = O1[1];
            asm("v_permlane32_swap_b32 %0, %1" : "+v"(a), "+v"(b));
            asm("v_permlane32_swap_b32 %0, %1" : "+v"(c), "+v"(d));
            uint4 w = {a, c, b, d};
            s16x8 bf = __builtin_bit_cast(s16x8, w);
            pv0 = mfma32(v00, bf, pv0);
            pv1 = mfma32(v10, bf, pv1);
        }
        {
            u32 a = O0[2], b = O0[3], c = O1[2], d = O1[3];
            asm("v_permlane32_swap_b32 %0, %1" : "+v"(a), "+v"(b));
            asm("v_permlane32_swap_b32 %0, %1" : "+v"(c), "+v"(d));
            uint4 w = {a, c, b, d};
            s16x8 bf = __builtin_bit_cast(s16x8, w);
            pv0 = mfma32(v01, bf, pv0);
            pv1 = mfma32(v11, bf, pv1);
        }

        // --- LDS transpose (double-buffered by parity) ---
        float* buf = &R[wid][(i & 1) * 1056];
#pragma unroll
        for (int r = 0; r < 16; r++)
            buf[ql * 33 + (r & 3) + 8 * (r >> 2) + 4 * h] = acc[r];

        // --- attn burst: nontemporal, issued last in the body ---
#pragma unroll
        for (int p = 0; p < 4; p++) {
            int q = p * 8 + (lane >> 3), j4 = (lane & 7) * 4;
            f32x4 o;
            o.x = buf[q * 33 + j4 + 0];
            o.y = buf[q * 33 + j4 + 1];
            o.z = buf[q * 33 + j4 + 2];
            o.w = buf[q * 33 + j4 + 3];
            __builtin_nontemporal_store(o,
                (f32x4*)&attn[((size_t)(bh * SQ + q0 + q)) * SKV + kt * 32 + j4]);
        }

#pragma unroll
        for (int c = 0; c < 4; c++) kA[c] = kB[c];
    }

    // ---- write PV partials to own LDS region ----
#pragma unroll
    for (int r = 0; r < 16; r++) {
        R[wid][r * 64 + lane]        = pv0[r];
        R[wid][1024 + r * 64 + lane] = pv1[r];
    }
    __syncthreads();

    // ---- waves 0,1 reduce 4 partials for d-half X=wid; ctx single bf16 ----
    if (wid < 2) {
        int X = wid;
        float s[16];
#pragma unroll
        for (int r = 0; r < 16; r++)
            s[r] = R[0][X * 1024 + r * 64 + lane] + R[1][X * 1024 + r * 64 + lane]
                 + R[2][X * 1024 + r * 64 + lane] + R[3][X * 1024 + r * 64 + lane];
        int b_ = bh >> 3, hh = bh & 7;
        size_t rowa = ((size_t)(b_ * SQ + q0 + ql)) * DMODEL + hh * 64 + X * 32 + 4 * h;
#pragma unroll
        for (int g = 0; g < 4; g++) {
            u16 hv[4];
#pragma unroll
            for (int i = 0; i < 4; i++) hv[i] = f2bf(s[4 * g + i]);
            *(ushort4*)(ch + rowa + 8 * g) = *(ushort4*)hv;
        }
    }
}

// ---------------------------------------------------------------------------
extern "C" void kernel_launch(void* const* d_in, const int* in_sizes, int n_in,
                              void* d_out, int out_size, void* d_ws, size_t ws_size,
                              hipStream_t stream)
{
    const float* x   = (const float*)d_in[0];
    const float* y   = (const float*)d_in[1];
    const float* lqg = (const float*)d_in[2];
    const float* lqb = (const float*)d_in[3];
    const float* lkg = (const float*)d_in[4];
    const float* lkb = (const float*)d_in[5];
    const float* Wq  = (const float*)d_in[6];
    const float* Wk  = (const float*)d_in[7];
    const float* Wv  = (const float*)d_in[8];
    const float* Wo  = (const float*)d_in[9];
    const float* bo  = (const float*)d_in[10];

    char* ws = (char*)d_ws;
    size_t off = 0;
    auto alloc = [&](size_t nelem) -> u16* {
        u16* p = (u16*)(ws + off);
        off += (nelem * 2 + 255) & ~(size_t)255;
        return p;
    };
    const size_t NROW = (size_t)MROWS * DMODEL;
    u16* xnh = alloc(NROW);  u16* xnl = alloc(NROW);
    u16* ynh = alloc(NROW);  u16* ynl = alloc(NROW);
    u16* wbase = alloc(4 * 2 * 262144);
    u16* wqh = wbase + 0 * 2 * 262144; u16* wql = wqh + 262144;
    u16* wkh = wbase + 1 * 2 * 262144; u16* wkl = wkh + 262144;
    u16* wvh = wbase + 2 * 2 * 262144;
    u16* woh = wbase + 3 * 2 * 262144;
    u16* qh_ = alloc(NROW);
    u16* kh_ = alloc(NROW);
    u16* vt_ = alloc(NROW);
    u16* ct_ = alloc(NROW);

    float* outp  = (float*)d_out;
    float* attnp = outp + (size_t)MROWS * DMODEL;

    ln_split_kernel<<<MROWS / 4, 256, 0, stream>>>(x, lqg, lqb, xnh, xnl);
    ln_split_kernel<<<MROWS / 4, 256, 0, stream>>>(y, lkg, lkb, ynh, ynl);
    wsplit_kernel<<<dim3(1024, 4), 256, 0, stream>>>(Wq, Wk, Wv, Wo, wbase, nullptr);

    dim3 gg(MROWS / 64, 512 / 64);
    gemm_split<3><<<gg, 256, 0, stream>>>(xnh, xnl, wqh, wql, qh_, nullptr, 0.125f);
    gemm_split<3><<<gg, 256, 0, stream>>>(ynh, ynl, wkh, wkl, kh_, nullptr, 1.0f);
    gemm_split<5><<<gg, 256, 0, stream>>>(ynh, nullptr, wvh, nullptr, vt_, nullptr, 1.0f);

    attn_kernel<<<2048, 256, 0, stream>>>(qh_, kh_, vt_, attnp, ct_);

    gemm_split<4><<<gg, 256, 0, stream>>>(ct_, nullptr, woh, nullptr, (void*)outp, bo, 1.0f);
}

// Round 19
// 260.374 us; speedup vs baseline: 1.9864x; 1.0635x over previous
//
#include <hip/hip_runtime.h>

typedef float f32x4 __attribute__((ext_vector_type(4)));
typedef float f32x16 __attribute__((ext_vector_type(16)));
typedef __bf16 bf16x8 __attribute__((ext_vector_type(8)));
typedef short s16x8 __attribute__((ext_vector_type(8)));
typedef unsigned short u16;
typedef unsigned int u32;

#define DEV static __device__ __forceinline__

constexpr int BATCH = 4;
constexpr int SQ    = 2048;
constexpr int SKV   = 2048;
constexpr int DMODEL= 512;
constexpr int NH    = 8;
constexpr int DH    = 64;
constexpr int MROWS = BATCH * SQ;      // 8192
constexpr float LN_EPS = 1e-5f;

DEV u16 f2bf(float f) {
    unsigned u = __builtin_bit_cast(unsigned, f);
    unsigned r = (u + 0x7FFFu + ((u >> 16) & 1u)) >> 16;
    return (u16)r;
}
DEV float bf2f(u16 h) { return __builtin_bit_cast(float, ((unsigned)h) << 16); }

DEV f32x4 mfma16(s16x8 a, s16x8 b, f32x4 c) {
    return __builtin_amdgcn_mfma_f32_16x16x32_bf16(
        __builtin_bit_cast(bf16x8, a), __builtin_bit_cast(bf16x8, b), c, 0, 0, 0);
}
DEV f32x16 mfma32(s16x8 a, s16x8 b, f32x16 c) {
    return __builtin_amdgcn_mfma_f32_32x32x16_bf16(
        __builtin_bit_cast(bf16x8, a), __builtin_bit_cast(bf16x8, b), c, 0, 0, 0);
}
DEV u32 cvtpk(float lo, float hi) {
    u32 r;
    asm("v_cvt_pk_bf16_f32 %0, %1, %2" : "=v"(r) : "v"(lo), "v"(hi));
    return r;
}

// ---------------------------------------------------------------------------
// LayerNorm -> bf16 (hi only; all downstream GEMMs are now 1-term except none
// needing lo). One wave per row of 512. Block = 4 rows.
// ---------------------------------------------------------------------------
__global__ __launch_bounds__(256) void ln_kernel(
    const float* __restrict__ X, const float* __restrict__ G, const float* __restrict__ Bt,
    u16* __restrict__ oh)
{
    int row  = blockIdx.x * 4 + (threadIdx.x >> 6);
    int lane = threadIdx.x & 63;
    const float4* xr = (const float4*)(X + (size_t)row * DMODEL);
    float4 a = xr[lane * 2], b = xr[lane * 2 + 1];
    float vv[8] = {a.x, a.y, a.z, a.w, b.x, b.y, b.z, b.w};
    float s = 0.f;
#pragma unroll
    for (int i = 0; i < 8; i++) s += vv[i];
#pragma unroll
    for (int o = 32; o; o >>= 1) s += __shfl_xor(s, o);
    float mu = s * (1.0f / DMODEL);
    float vs = 0.f;
#pragma unroll
    for (int i = 0; i < 8; i++) { float d = vv[i] - mu; vs += d * d; }
#pragma unroll
    for (int o = 32; o; o >>= 1) vs += __shfl_xor(vs, o);
    float rstd = rsqrtf(vs * (1.0f / DMODEL) + LN_EPS);

    const float4* g4 = (const float4*)G;
    const float4* b4 = (const float4*)Bt;
    float4 g0 = g4[lane * 2], g1 = g4[lane * 2 + 1];
    float4 c0 = b4[lane * 2], c1 = b4[lane * 2 + 1];
    float gg[8] = {g0.x, g0.y, g0.z, g0.w, g1.x, g1.y, g1.z, g1.w};
    float cc[8] = {c0.x, c0.y, c0.z, c0.w, c1.x, c1.y, c1.z, c1.w};

    s16x8 vh;
#pragma unroll
    for (int i = 0; i < 8; i++) {
        float t = (vv[i] - mu) * rstd * gg[i] + cc[i];
        vh[i] = (short)f2bf(t);
    }
    *(s16x8*)(oh + (size_t)row * DMODEL + lane * 8) = vh;
}

// ---------------------------------------------------------------------------
// Weight transpose -> bf16 (hi only), all 4 weights in one launch
// ---------------------------------------------------------------------------
__global__ __launch_bounds__(256) void wsplit_kernel(
    const float* __restrict__ W0, const float* __restrict__ W1,
    const float* __restrict__ W2, const float* __restrict__ W3,
    u16* __restrict__ t0)
{
    int which = blockIdx.y;
    const float* W = which == 0 ? W0 : which == 1 ? W1 : which == 2 ? W2 : W3;
    u16* th = t0 + (size_t)which * 262144;
    int idx = blockIdx.x * 256 + threadIdx.x;     // idx = n*512 + k
    int n = idx >> 9, k = idx & 511;
    th[idx] = f2bf(W[(size_t)k * 512 + n]);
}

// ---------------------------------------------------------------------------
// 1-term bf16 GEMM. MODE 6: scaled bf16 out at (b,h,s,d)   (Q/K)
//                   MODE 5: bf16 V^T out at (b,h,d,s)       (V)
//                   MODE 4: fp32 + bias out                 (out)
// ---------------------------------------------------------------------------
template<int MODE>
__global__ __launch_bounds__(256) void gemm_bf16(
    const u16* __restrict__ Ah, const u16* __restrict__ Bh,
    void* __restrict__ out0, const float* __restrict__ bias, float scl)
{
    constexpr int K  = 512;
    constexpr int LS = 72;
    __shared__ u16 lA[64][LS];
    __shared__ u16 lB[64][LS];

    int bm = blockIdx.x, bn = blockIdx.y;
    int tid = threadIdx.x, lane = tid & 63, wv = tid >> 6;
    int wm = (wv >> 1) * 32, wn = (wv & 1) * 32;
    int srow = tid >> 3, scol = (tid & 7) * 8;
    const size_t aoff0 = ((size_t)(bm * 64 + srow)) * K + scol;
    const size_t aoff1 = ((size_t)(bm * 64 + srow + 32)) * K + scol;
    const size_t boff0 = ((size_t)(bn * 64 + srow)) * K + scol;
    const size_t boff1 = ((size_t)(bn * 64 + srow + 32)) * K + scol;

    f32x4 acc[2][2] = {};

    for (int k0 = 0; k0 < K; k0 += 64) {
        *(int4*)&lA[srow][scol]      = *(const int4*)(Ah + aoff0 + k0);
        *(int4*)&lA[srow + 32][scol] = *(const int4*)(Ah + aoff1 + k0);
        *(int4*)&lB[srow][scol]      = *(const int4*)(Bh + boff0 + k0);
        *(int4*)&lB[srow + 32][scol] = *(const int4*)(Bh + boff1 + k0);
        __syncthreads();
        int fr = lane & 15, fg = (lane >> 4) * 8;
#pragma unroll
        for (int kk = 0; kk < 64; kk += 32) {
            s16x8 ah[2], bh[2];
#pragma unroll
            for (int m_ = 0; m_ < 2; m_++)
                ah[m_] = *(const s16x8*)&lA[wm + m_ * 16 + fr][kk + fg];
#pragma unroll
            for (int n_ = 0; n_ < 2; n_++)
                bh[n_] = *(const s16x8*)&lB[wn + n_ * 16 + fr][kk + fg];
#pragma unroll
            for (int m_ = 0; m_ < 2; m_++)
#pragma unroll
                for (int n_ = 0; n_ < 2; n_++)
                    acc[m_][n_] = mfma16(ah[m_], bh[n_], acc[m_][n_]);
        }
        __syncthreads();
    }

    int fr = lane & 15, fq = lane >> 4;
#pragma unroll
    for (int m_ = 0; m_ < 2; m_++)
#pragma unroll
        for (int n_ = 0; n_ < 2; n_++)
#pragma unroll
            for (int r = 0; r < 4; r++) {
                int gm = bm * 64 + wm + m_ * 16 + fq * 4 + r;
                int gn = bn * 64 + wn + n_ * 16 + fr;
                float v = acc[m_][n_][r];
                if (MODE == 6) {
                    v *= scl;
                    int b_ = gm >> 11, s_ = gm & 2047, h_ = gn >> 6, d_ = gn & 63;
                    size_t adr = (((size_t)(b_ * NH + h_)) * SKV + s_) * DH + d_;
                    ((u16*)out0)[adr] = f2bf(v);
                } else if (MODE == 5) {
                    int b_ = gm >> 11, s_ = gm & 2047, h_ = gn >> 6, d_ = gn & 63;
                    size_t adr = (((size_t)(b_ * NH + h_)) * DH + d_) * SKV + s_;
                    ((u16*)out0)[adr] = f2bf(v);
                } else {
                    v += bias[gn];
                    ((float*)out0)[(size_t)gm * DMODEL + gn] = v;
                }
            }
}

// ---------------------------------------------------------------------------
// Streaming attention (R17 verified body; only change: launch_bounds(256,4)).
// One block = one 32-q-row tile, 4 waves; wave w owns kv quarter (16 tiles).
// Pass 1: rowsum of exp(S). Pass 2: K prefetched one tile ahead, normalized
// P packed to bf16 for PV, attn coalesced via per-wave LDS transpose,
// nontemporal f32x4 stores. ctx written single bf16.
//
// Layouts (mfma_f32_32x32x16_bf16, measured m74/m101):
//   A/B frag: row(col) = lane&31, k = 8*(lane>>5) + j, j=0..7
//   C:        col = lane&31,     row = (r&3) + 8*(r>>2) + 4*(lane>>5)
// NOTE: swapped QK^T => q lane-local; attn rows live ACROSS lanes => LDS
// transpose required for coalesced attn stores (round-8 lesson).
// VGPR demand measured 64 (R15/R17) => (256,4) cap of 128 forces no spill.
// ---------------------------------------------------------------------------
__global__ __launch_bounds__(256, 4) void attn_kernel(
    const u16* __restrict__ Qh, const u16* __restrict__ Kh,
    const u16* __restrict__ VT,
    float* __restrict__ attn, u16* __restrict__ ch)
{
    __shared__ float R[4][2112];       // per-wave: 2 transpose bufs (2x1056) / PV partials (2048)
    __shared__ float rs[4][32];
    int tid = threadIdx.x, lane = tid & 63, wid = tid >> 6;
    int h  = lane >> 5;
    int ql = lane & 31;
    int off = 8 * h;

    // XCD-chunked bijective swizzle: 2048 blocks, 8 XCDs x 256; 4 bh per XCD
    int vb = (blockIdx.x & 7) * 256 + (blockIdx.x >> 3);
    int bh = vb >> 6;
    int qt = vb & 63;
    int q0 = qt * 32;
    const size_t base = (size_t)bh * (SKV * DH);
    int kt0 = wid * 16;

    // ---- Q B-fragments: Q[q0+ql][16c + 8h + 0..7] ----
    s16x8 qf[4];
    {
        const u16* qp = Qh + base + ((size_t)(q0 + ql)) * DH + off;
#pragma unroll
        for (int c = 0; c < 4; c++) qf[c] = *(const s16x8*)(qp + c * 16);
    }

    // ---- pass 1: partial rowsum of exp(S) ----
    float rsum0 = 0.f, rsum1 = 0.f;
    for (int kt = kt0; kt < kt0 + 16; kt++) {
        size_t kb = base + ((size_t)(kt * 32 + ql)) * DH + off;
        s16x8 kh[4];
#pragma unroll
        for (int c = 0; c < 4; c++) kh[c] = *(const s16x8*)(Kh + kb + c * 16);
        f32x16 a1 = 0;
#pragma unroll
        for (int c = 0; c < 4; c++) a1 = mfma32(kh[c], qf[c], a1);
#pragma unroll
        for (int r = 0; r < 16; r += 2) {
            rsum0 += __expf(a1[r]);
            rsum1 += __expf(a1[r + 1]);
        }
    }
    float rsum = rsum0 + rsum1;
    rsum += __shfl_xor(rsum, 32);
    if (lane < 32) rs[wid][ql] = rsum;
    __syncthreads();
    float inv_l = 1.0f / (rs[0][ql] + rs[1][ql] + rs[2][ql] + rs[3][ql]);

    // ---- pass 2: K prefetched one tile ahead; stores issued last ----
    f32x16 pv0 = 0, pv1 = 0;
    const u16* vbase = VT + (size_t)bh * (DH * SKV) + (size_t)ql * SKV + off;

    s16x8 kA[4];
    {
        size_t kb = base + ((size_t)(kt0 * 32 + ql)) * DH + off;
#pragma unroll
        for (int c = 0; c < 4; c++) kA[c] = *(const s16x8*)(Kh + kb + c * 16);
    }

    for (int i = 0; i < 16; i++) {
        int kt = kt0 + i;
        // --- issue this tile's V loads early (before any stores this body) ---
        const u16* vp = vbase + kt * 32;
        s16x8 v00 = *(const s16x8*)(vp);
        s16x8 v01 = *(const s16x8*)(vp + 16);
        s16x8 v10 = *(const s16x8*)(vp + (size_t)32 * SKV);
        s16x8 v11 = *(const s16x8*)(vp + (size_t)32 * SKV + 16);
        // --- issue next tile's K prefetch ---
        s16x8 kB[4];
        if (i + 1 < 16) {
            size_t kb = base + ((size_t)((kt + 1) * 32 + ql)) * DH + off;
#pragma unroll
            for (int c = 0; c < 4; c++) kB[c] = *(const s16x8*)(Kh + kb + c * 16);
        }
        // --- QK^T from prefetched regs ---
        f32x16 acc = 0;
#pragma unroll
        for (int c = 0; c < 4; c++) acc = mfma32(kA[c], qf[c], acc);
#pragma unroll
        for (int r = 0; r < 16; r++) acc[r] = __expf(acc[r]) * inv_l;

        // --- PV: pack to bf16 + permlane -> B-frags ---
        u32 O0[4], O1[4];
#pragma unroll
        for (int g = 0; g < 4; g++) {
            O0[g] = cvtpk(acc[4 * g + 0], acc[4 * g + 1]);
            O1[g] = cvtpk(acc[4 * g + 2], acc[4 * g + 3]);
        }
        {
            u32 a = O0[0], b = O0[1], c = O1[0], d = O1[1];
            asm("v_permlane32_swap_b32 %0, %1" : "+v"(a), "+v"(b));
            asm("v_permlane32_swap_b32 %0, %1" : "+v"(c), "+v"(d));
            uint4 w = {a, c, b, d};
            s16x8 bf = __builtin_bit_cast(s16x8, w);
            pv0 = mfma32(v00, bf, pv0);
            pv1 = mfma32(v10, bf, pv1);
        }
        {
            u32 a = O0[2], b = O0[3], c = O1[2], d = O1[3];
            asm("v_permlane32_swap_b32 %0, %1" : "+v"(a), "+v"(b));
            asm("v_permlane32_swap_b32 %0, %1" : "+v"(c), "+v"(d));
            uint4 w = {a, c, b, d};
            s16x8 bf = __builtin_bit_cast(s16x8, w);
            pv0 = mfma32(v01, bf, pv0);
            pv1 = mfma32(v11, bf, pv1);
        }

        // --- LDS transpose (double-buffered by parity) ---
        float* buf = &R[wid][(i & 1) * 1056];
#pragma unroll
        for (int r = 0; r < 16; r++)
            buf[ql * 33 + (r & 3) + 8 * (r >> 2) + 4 * h] = acc[r];

        // --- attn burst: nontemporal, issued last in the body ---
#pragma unroll
        for (int p = 0; p < 4; p++) {
            int q = p * 8 + (lane >> 3), j4 = (lane & 7) * 4;
            f32x4 o;
            o.x = buf[q * 33 + j4 + 0];
            o.y = buf[q * 33 + j4 + 1];
            o.z = buf[q * 33 + j4 + 2];
            o.w = buf[q * 33 + j4 + 3];
            __builtin_nontemporal_store(o,
                (f32x4*)&attn[((size_t)(bh * SQ + q0 + q)) * SKV + kt * 32 + j4]);
        }

#pragma unroll
        for (int c = 0; c < 4; c++) kA[c] = kB[c];
    }

    // ---- write PV partials to own LDS region ----
#pragma unroll
    for (int r = 0; r < 16; r++) {
        R[wid][r * 64 + lane]        = pv0[r];
        R[wid][1024 + r * 64 + lane] = pv1[r];
    }
    __syncthreads();

    // ---- waves 0,1 reduce 4 partials for d-half X=wid; ctx single bf16 ----
    if (wid < 2) {
        int X = wid;
        float s[16];
#pragma unroll
        for (int r = 0; r < 16; r++)
            s[r] = R[0][X * 1024 + r * 64 + lane] + R[1][X * 1024 + r * 64 + lane]
                 + R[2][X * 1024 + r * 64 + lane] + R[3][X * 1024 + r * 64 + lane];
        int b_ = bh >> 3, hh = bh & 7;
        size_t rowa = ((size_t)(b_ * SQ + q0 + ql)) * DMODEL + hh * 64 + X * 32 + 4 * h;
#pragma unroll
        for (int g = 0; g < 4; g++) {
            u16 hv[4];
#pragma unroll
            for (int i = 0; i < 4; i++) hv[i] = f2bf(s[4 * g + i]);
            *(ushort4*)(ch + rowa + 8 * g) = *(ushort4*)hv;
        }
    }
}

// ---------------------------------------------------------------------------
extern "C" void kernel_launch(void* const* d_in, const int* in_sizes, int n_in,
                              void* d_out, int out_size, void* d_ws, size_t ws_size,
                              hipStream_t stream)
{
    const float* x   = (const float*)d_in[0];
    const float* y   = (const float*)d_in[1];
    const float* lqg = (const float*)d_in[2];
    const float* lqb = (const float*)d_in[3];
    const float* lkg = (const float*)d_in[4];
    const float* lkb = (const float*)d_in[5];
    const float* Wq  = (const float*)d_in[6];
    const float* Wk  = (const float*)d_in[7];
    const float* Wv  = (const float*)d_in[8];
    const float* Wo  = (const float*)d_in[9];
    const float* bo  = (const float*)d_in[10];

    char* ws = (char*)d_ws;
    size_t off = 0;
    auto alloc = [&](size_t nelem) -> u16* {
        u16* p = (u16*)(ws + off);
        off += (nelem * 2 + 255) & ~(size_t)255;
        return p;
    };
    const size_t NROW = (size_t)MROWS * DMODEL;
    u16* xnh = alloc(NROW);
    u16* ynh = alloc(NROW);
    u16* wbase = alloc(4 * 262144);          // [which][262144] hi-only
    u16* wqh = wbase + 0 * 262144;
    u16* wkh = wbase + 1 * 262144;
    u16* wvh = wbase + 2 * 262144;
    u16* woh = wbase + 3 * 262144;
    u16* qh_ = alloc(NROW);
    u16* kh_ = alloc(NROW);
    u16* vt_ = alloc(NROW);
    u16* ct_ = alloc(NROW);

    float* outp  = (float*)d_out;
    float* attnp = outp + (size_t)MROWS * DMODEL;

    ln_kernel<<<MROWS / 4, 256, 0, stream>>>(x, lqg, lqb, xnh);
    ln_kernel<<<MROWS / 4, 256, 0, stream>>>(y, lkg, lkb, ynh);
    wsplit_kernel<<<dim3(1024, 4), 256, 0, stream>>>(Wq, Wk, Wv, Wo, wbase);

    dim3 gg(MROWS / 64, 512 / 64);
    gemm_bf16<6><<<gg, 256, 0, stream>>>(xnh, wqh, qh_, nullptr, 0.125f);
    gemm_bf16<6><<<gg, 256, 0, stream>>>(ynh, wkh, kh_, nullptr, 1.0f);
    gemm_bf16<5><<<gg, 256, 0, stream>>>(ynh, wvh, vt_, nullptr, 1.0f);

    attn_kernel<<<2048, 256, 0, stream>>>(qh_, kh_, vt_, attnp, ct_);

    gemm_bf16<4><<<gg, 256, 0, stream>>>(ct_, woh, (void*)outp, bo, 1.0f);
}